// Round 19
// baseline (3234.330 us; speedup 1.0000x reference)
//
#include <hip/hip_runtime.h>
#include <hip/hip_bf16.h>

// Problem constants
#define BB_ 8
#define NVEC 4096
#define DIM 512
#define HEADS 8
#define DH 64
#define MM_ 256
#define ITERS 6
#define DEPTH 2
#define NCLASS 10
#define KER 33
#define INNER 512
#define LSEG 16  // NVEC / MM_

typedef long long ll;
typedef __bf16 bh16;
typedef __attribute__((ext_vector_type(8))) __bf16 bf16x8;
typedef __attribute__((ext_vector_type(4))) float f32x4;

// ===========================================================================
// MFMA bf16 GEMM. TRB=0 (TN): C = A[M,K] @ B_t[N,K]^T. TRB=1 (NN).
// Tile BM=WR*64 x BN=WC*64, BK=32, 256 threads = 4 waves (WR*WC==4).
// XCD-bijective block swizzle (m204). SMAX: fused row-softmax (WR==1,
// gridDim.x==1). DUAL: C=acc, C2=diagv*I-acc. Batch: z -> bo=z/BI, bi=z%BI.
// ===========================================================================
template<int WR, int WC, bool TRB, bool GELU_ACT, bool RESID, bool BF16OUT,
         bool DUAL, bool SMAX>
__global__ void __launch_bounds__(256)
mgemm_k(const bh16* __restrict__ A, const bh16* __restrict__ B,
        const float* __restrict__ bias, void* __restrict__ Cv, void* __restrict__ C2v,
        int K, int lda, int ldb, int ldc,
        int BI, ll sAo, ll sAi, ll sBo, ll sBi, ll sCo, ll sCi,
        float alpha, float diagv)
{
    constexpr int BM = WR * 64, BN = WC * 64;
    const int bz = blockIdx.z;
    const int bo = bz / BI, bi = bz % BI;
    const bh16* Ab = A + bo * sAo + (ll)bi * sAi;
    const bh16* Bb = B + bo * sBo + (ll)bi * sBi;
    const ll coff = bo * sCo + (ll)bi * sCi;

    const int gx = gridDim.x;
    const int nwg = gx * gridDim.y;
    int flat = blockIdx.y * gx + blockIdx.x;
    {
        int xcd = flat & 7, base = flat >> 3;
        int q = nwg >> 3, rr = nwg & 7;
        flat = (xcd < rr ? xcd * (q + 1) : rr * (q + 1) + (xcd - rr) * q) + base;
    }
    const int m0 = (flat / gx) * BM;
    const int n0 = (flat % gx) * BN;

    const int tid = threadIdx.x;
    const int lane = tid & 63;
    const int wave = tid >> 6;
    const int wr = wave / WC, wc = wave % WC;

    __shared__ bh16 Al[BM * 32];
    __shared__ bh16 Bl[BN * 32];
    __shared__ float srow[SMAX ? 4 * 64 : 4];

    f32x4 acc[4][4];
#pragma unroll
    for (int i = 0; i < 4; ++i)
#pragma unroll
        for (int j = 0; j < 4; ++j) acc[i][j] = (f32x4){0.f, 0.f, 0.f, 0.f};

    const int srowi = tid >> 2;  // 0..63
    const int ssl   = tid & 3;   // 16B slot (linear LDS dest)

    const int rsel  = ((lane & 15) >> 1) & 3;
    const int kslot = lane >> 4;

    for (int k0 = 0; k0 < K; k0 += 32) {
        __syncthreads();
#pragma unroll
        for (int i = 0; i < BM / 64; ++i) {
            int row = i * 64 + srowi;
            int gsl = ssl ^ ((row >> 1) & 3);
            __builtin_amdgcn_global_load_lds(
                (const __attribute__((address_space(1))) unsigned int*)
                    (Ab + (ll)(m0 + row) * lda + k0 + gsl * 8),
                (__attribute__((address_space(3))) unsigned int*)
                    (Al + row * 32 + ssl * 8),
                16, 0, 0);
        }
        if (!TRB) {
#pragma unroll
            for (int i = 0; i < BN / 64; ++i) {
                int row = i * 64 + srowi;
                int gsl = ssl ^ ((row >> 1) & 3);
                __builtin_amdgcn_global_load_lds(
                    (const __attribute__((address_space(1))) unsigned int*)
                        (Bb + (ll)(n0 + row) * ldb + k0 + gsl * 8),
                    (__attribute__((address_space(3))) unsigned int*)
                        (Bl + row * 32 + ssl * 8),
                    16, 0, 0);
            }
        } else {
            const int bk = tid >> 3;
            const int nb0 = (tid & 7) * (BN / 8);
#pragma unroll
            for (int v8 = 0; v8 < BN / 64; ++v8) {
                int nb = nb0 + v8 * 8;
                bf16x8 v = *(const bf16x8*)(Bb + (ll)(k0 + bk) * ldb + n0 + nb);
#pragma unroll
                for (int j = 0; j < 8; ++j) {
                    int n = nb + j;
                    int sl = (bk >> 3) ^ ((n >> 1) & 3);
                    Bl[n * 32 + sl * 8 + (bk & 7)] = v[j];
                }
            }
        }
        __syncthreads();

        bf16x8 af[4], bfr[4];
#pragma unroll
        for (int mi = 0; mi < 4; ++mi) {
            int row = wr * 64 + mi * 16 + (lane & 15);
            af[mi] = *(const bf16x8*)(Al + row * 32 + (kslot ^ rsel) * 8);
        }
#pragma unroll
        for (int ni = 0; ni < 4; ++ni) {
            int row = wc * 64 + ni * 16 + (lane & 15);
            bfr[ni] = *(const bf16x8*)(Bl + row * 32 + (kslot ^ rsel) * 8);
        }
#pragma unroll
        for (int mi = 0; mi < 4; ++mi)
#pragma unroll
            for (int ni = 0; ni < 4; ++ni)
                acc[mi][ni] = __builtin_amdgcn_mfma_f32_16x16x32_bf16(
                    af[mi], bfr[ni], acc[mi][ni], 0, 0, 0);
    }

    if (SMAX) {
        bh16* Cb = (bh16*)Cv;
#pragma unroll
        for (int mi = 0; mi < 4; ++mi)
#pragma unroll
            for (int ni = 0; ni < 4; ++ni)
#pragma unroll
                for (int r = 0; r < 4; ++r) acc[mi][ni][r] *= alpha;
        float mx[4][4];
#pragma unroll
        for (int mi = 0; mi < 4; ++mi)
#pragma unroll
            for (int r = 0; r < 4; ++r) {
                float m_ = acc[mi][0][r];
#pragma unroll
                for (int ni = 1; ni < 4; ++ni) m_ = fmaxf(m_, acc[mi][ni][r]);
#pragma unroll
                for (int msk = 1; msk < 16; msk <<= 1)
                    m_ = fmaxf(m_, __shfl_xor(m_, msk));
                mx[mi][r] = m_;
            }
        if ((lane & 15) == 0) {
#pragma unroll
            for (int mi = 0; mi < 4; ++mi)
#pragma unroll
                for (int r = 0; r < 4; ++r)
                    srow[wc * 64 + mi * 16 + (lane >> 4) * 4 + r] = mx[mi][r];
        }
        __syncthreads();
        float M_[4][4];
#pragma unroll
        for (int mi = 0; mi < 4; ++mi)
#pragma unroll
            for (int r = 0; r < 4; ++r) {
                int row = mi * 16 + (lane >> 4) * 4 + r;
                M_[mi][r] = fmaxf(fmaxf(srow[row], srow[64 + row]),
                                  fmaxf(srow[128 + row], srow[192 + row]));
            }
        __syncthreads();
        float sm[4][4];
#pragma unroll
        for (int mi = 0; mi < 4; ++mi)
#pragma unroll
            for (int r = 0; r < 4; ++r) {
                float s_ = 0.f;
#pragma unroll
                for (int ni = 0; ni < 4; ++ni) {
                    float e = __expf(acc[mi][ni][r] - M_[mi][r]);
                    acc[mi][ni][r] = e;
                    s_ += e;
                }
#pragma unroll
                for (int msk = 1; msk < 16; msk <<= 1)
                    s_ += __shfl_xor(s_, msk);
                sm[mi][r] = s_;
            }
        if ((lane & 15) == 0) {
#pragma unroll
            for (int mi = 0; mi < 4; ++mi)
#pragma unroll
                for (int r = 0; r < 4; ++r)
                    srow[wc * 64 + mi * 16 + (lane >> 4) * 4 + r] = sm[mi][r];
        }
        __syncthreads();
#pragma unroll
        for (int mi = 0; mi < 4; ++mi)
#pragma unroll
            for (int r = 0; r < 4; ++r) {
                int row = mi * 16 + (lane >> 4) * 4 + r;
                float inv = 1.0f / (srow[row] + srow[64 + row] +
                                    srow[128 + row] + srow[192 + row]);
                int rowg = m0 + row;
#pragma unroll
                for (int ni = 0; ni < 4; ++ni) {
                    int colg = n0 + wc * 64 + ni * 16 + (lane & 15);
                    Cb[coff + (ll)rowg * ldc + colg] = (bh16)(acc[mi][ni][r] * inv);
                }
            }
        return;
    }

#pragma unroll
    for (int mi = 0; mi < 4; ++mi) {
#pragma unroll
        for (int ni = 0; ni < 4; ++ni) {
            const int colg = n0 + wc * 64 + ni * 16 + (lane & 15);
            const float bia = (!DUAL && bias) ? bias[colg] : 0.f;
#pragma unroll
            for (int r = 0; r < 4; ++r) {
                const int rowg = m0 + wr * 64 + mi * 16 + (lane >> 4) * 4 + r;
                const float a = acc[mi][ni][r];
                const ll off = coff + (ll)rowg * ldc + colg;
                if (DUAL) {
                    ((bh16*)Cv)[off] = (bh16)a;
                    float w = ((rowg == colg) ? diagv : 0.f) - a;
                    ((bh16*)C2v)[off] = (bh16)w;
                } else {
                    float v = alpha * a + bia;
                    if (diagv != 0.f && rowg == colg) v += diagv;
                    if (GELU_ACT) {
                        float t = tanhf(0.7978845608f * (v + 0.044715f * v * v * v));
                        v = 0.5f * v * (1.0f + t);
                    }
                    if (BF16OUT) {
                        ((bh16*)Cv)[off] = (bh16)v;
                    } else {
                        float* p = (float*)Cv + off;
                        float o = v;
                        if (RESID) o += *p;
                        *p = o;
                    }
                }
            }
        }
    }
}

template<int WR, int WC, bool TRB, bool G, bool R, bool BO, bool D, bool SX>
static inline void mg(hipStream_t s, int M, int N, int K,
                      const bh16* A, int lda, const bh16* B, int ldb,
                      void* C, int ldc, void* C2, const float* bias,
                      int batch, int BI,
                      ll sAo, ll sAi, ll sBo, ll sBi, ll sCo, ll sCi,
                      float alpha, float diagv)
{
    dim3 grid(N / (WC * 64), M / (WR * 64), batch);
    hipLaunchKernelGGL((mgemm_k<WR, WC, TRB, G, R, BO, D, SX>), grid, dim3(256), 0, s,
                       A, B, bias, C, C2, K, lda, ldb, ldc, BI,
                       sAo, sAi, sBo, sBi, sCo, sCi, alpha, diagv);
}

// ===========================================================================
// Fused attn1. Block = (16 q-rows, one (b,h)) -- quartered q-block for 4x TLP
// vs Round-14 (fattn is latency-bound; QB 64->32 measured +15%: 114->99 us,
// occ 20->40%). Per-row math BIT-IDENTICAL (same MFMA chains, same softmax
// tree, same rounding sites); only the block decomposition changes.
// Phase 1: S=q@kl^T (K=64), cross-wave softmax (alpha 0.125), P -> LDS
//   (pitch 264, linear). Phase 2: wave-K-split + f32 LDS reduce (pitch 68)
//   aliased over Pl (barrier-separated). Vectorized epilogue + conv.
// ===========================================================================
#define QB_ROWS 16
#define MI_FR (QB_ROWS / 16)
#define PPITCH 264
#define RPITCH 68
__global__ void __launch_bounds__(256)
fattn_k(const bh16* __restrict__ qkv, const bh16* __restrict__ klb,
        const bh16* __restrict__ wbt, bh16* __restrict__ aout)
{
    const int qb = blockIdx.x;          // 0..255
    const int bh = blockIdx.y;          // 0..63
    const int b = bh >> 3, h = bh & 7;
    const int q0 = qb * QB_ROWS;
    const int tid = threadIdx.x, lane = tid & 63, wave = tid >> 6;
    const ll SMPq = (ll)NVEC * 1536;

    __shared__ __align__(16) char smem[QB_ROWS * PPITCH * 2];  // 8,448 B
    bh16*  Pl  = (bh16*)smem;                                  // phase 1-2a
    float* red = (float*)smem;                                 // phase 2b (aliased)
    __shared__ float srow[4 * QB_ROWS];                        // 256 B

    const bh16* qbase = qkv + (ll)b * SMPq + (ll)q0 * 1536 + h * 64;
    const bh16* klbh = klb + (ll)bh * 16384;
    const bh16* wbh  = wbt + (ll)bh * 16384;

    const int kslot = lane >> 4;

    // ---- phase 1: scores (wave covers cols wave*64..wave*64+63) ----
    f32x4 acc[MI_FR][4];
#pragma unroll
    for (int i = 0; i < MI_FR; ++i)
#pragma unroll
        for (int j = 0; j < 4; ++j) acc[i][j] = (f32x4){0.f, 0.f, 0.f, 0.f};
#pragma unroll
    for (int ks = 0; ks < 2; ++ks) {
        int k0 = ks * 32;
        bf16x8 af[MI_FR], bfr[4];
#pragma unroll
        for (int mi = 0; mi < MI_FR; ++mi) {
            int row = mi * 16 + (lane & 15);
            af[mi] = *(const bf16x8*)(qbase + (ll)row * 1536 + k0 + kslot * 8);
        }
#pragma unroll
        for (int ni = 0; ni < 4; ++ni) {
            int brow = wave * 64 + ni * 16 + (lane & 15);
            bfr[ni] = *(const bf16x8*)(klbh + brow * 64 + k0 + kslot * 8);
        }
#pragma unroll
        for (int mi = 0; mi < MI_FR; ++mi)
#pragma unroll
            for (int ni = 0; ni < 4; ++ni)
                acc[mi][ni] = __builtin_amdgcn_mfma_f32_16x16x32_bf16(
                    af[mi], bfr[ni], acc[mi][ni], 0, 0, 0);
    }

    // ---- softmax over 256 cols (4 wave-quadrants) ----
#pragma unroll
    for (int mi = 0; mi < MI_FR; ++mi)
#pragma unroll
        for (int ni = 0; ni < 4; ++ni)
#pragma unroll
            for (int r = 0; r < 4; ++r) acc[mi][ni][r] *= 0.125f;
    float mx[MI_FR][4];
#pragma unroll
    for (int mi = 0; mi < MI_FR; ++mi)
#pragma unroll
        for (int r = 0; r < 4; ++r) {
            float m_ = acc[mi][0][r];
#pragma unroll
            for (int ni = 1; ni < 4; ++ni) m_ = fmaxf(m_, acc[mi][ni][r]);
#pragma unroll
            for (int msk = 1; msk < 16; msk <<= 1)
                m_ = fmaxf(m_, __shfl_xor(m_, msk));
            mx[mi][r] = m_;
        }
    if ((lane & 15) == 0) {
#pragma unroll
        for (int mi = 0; mi < MI_FR; ++mi)
#pragma unroll
            for (int r = 0; r < 4; ++r)
                srow[wave * QB_ROWS + mi * 16 + (lane >> 4) * 4 + r] = mx[mi][r];
    }
    __syncthreads();
    float M_[MI_FR][4];
#pragma unroll
    for (int mi = 0; mi < MI_FR; ++mi)
#pragma unroll
        for (int r = 0; r < 4; ++r) {
            int row = mi * 16 + (lane >> 4) * 4 + r;
            M_[mi][r] = fmaxf(fmaxf(srow[row], srow[QB_ROWS + row]),
                              fmaxf(srow[2 * QB_ROWS + row], srow[3 * QB_ROWS + row]));
        }
    __syncthreads();
    float sm[MI_FR][4];
#pragma unroll
    for (int mi = 0; mi < MI_FR; ++mi)
#pragma unroll
        for (int r = 0; r < 4; ++r) {
            float s_ = 0.f;
#pragma unroll
            for (int ni = 0; ni < 4; ++ni) {
                float e = __expf(acc[mi][ni][r] - M_[mi][r]);
                acc[mi][ni][r] = e;
                s_ += e;
            }
#pragma unroll
            for (int msk = 1; msk < 16; msk <<= 1)
                s_ += __shfl_xor(s_, msk);
            sm[mi][r] = s_;
        }
    if ((lane & 15) == 0) {
#pragma unroll
        for (int mi = 0; mi < MI_FR; ++mi)
#pragma unroll
            for (int r = 0; r < 4; ++r)
                srow[wave * QB_ROWS + mi * 16 + (lane >> 4) * 4 + r] = sm[mi][r];
    }
    __syncthreads();
    // normalize + write P (row pitch 264, linear)
#pragma unroll
    for (int mi = 0; mi < MI_FR; ++mi)
#pragma unroll
        for (int r = 0; r < 4; ++r) {
            int row = mi * 16 + (lane >> 4) * 4 + r;
            float inv = 1.0f / (srow[row] + srow[QB_ROWS + row] +
                                srow[2 * QB_ROWS + row] + srow[3 * QB_ROWS + row]);
#pragma unroll
            for (int ni = 0; ni < 4; ++ni) {
                int col = wave * 64 + ni * 16 + (lane & 15);
                Pl[row * PPITCH + col] = (bh16)(acc[mi][ni][r] * inv);
            }
        }
    __syncthreads();

    // ---- phase 2a: wave-K-split MFMA (wave w covers k = w*64 .. w*64+63) ----
    f32x4 acc2[MI_FR][4];
#pragma unroll
    for (int i = 0; i < MI_FR; ++i)
#pragma unroll
        for (int j = 0; j < 4; ++j) acc2[i][j] = (f32x4){0.f, 0.f, 0.f, 0.f};
#pragma unroll
    for (int kk = 0; kk < 2; ++kk) {
        int k0 = wave * 64 + kk * 32;
        bf16x8 af[MI_FR], bfr[4];
#pragma unroll
        for (int mi = 0; mi < MI_FR; ++mi) {
            int row = mi * 16 + (lane & 15);
            af[mi] = *(const bf16x8*)(Pl + row * PPITCH + k0 + kslot * 8);
        }
#pragma unroll
        for (int ni = 0; ni < 4; ++ni) {
            int brow = ni * 16 + (lane & 15);
            bfr[ni] = *(const bf16x8*)(wbh + brow * 256 + k0 + kslot * 8);
        }
#pragma unroll
        for (int mi = 0; mi < MI_FR; ++mi)
#pragma unroll
            for (int ni = 0; ni < 4; ++ni)
                acc2[mi][ni] = __builtin_amdgcn_mfma_f32_16x16x32_bf16(
                    af[mi], bfr[ni], acc2[mi][ni], 0, 0, 0);
    }
    __syncthreads();   // all Pl reads complete before red overlays smem

    // ---- phase 2b: deterministic 4-wave f32 reduce (pitch 68, 2-way) ----
    for (int w = 0; w < 4; ++w) {
        if (wave == w) {
#pragma unroll
            for (int mi = 0; mi < MI_FR; ++mi)
#pragma unroll
                for (int ni = 0; ni < 4; ++ni)
#pragma unroll
                    for (int r = 0; r < 4; ++r) {
                        int row = mi * 16 + (lane >> 4) * 4 + r;
                        int col = ni * 16 + (lane & 15);
                        if (w == 0) red[row * RPITCH + col] = acc2[mi][ni][r];
                        else        red[row * RPITCH + col] += acc2[mi][ni][r];
                    }
        }
        __syncthreads();
    }

    // ---- epilogue: + conv (bf16, QKV k-slot), round, vectorized write ----
    {
        const int row = tid >> 4;              // 0..15
        const int col0 = (tid & 15) * 4;       // 0,4,...,60
        const ll nrow = (ll)(q0 + row);
        const bh16* cv = qkv + (ll)b * SMPq + nrow * 1536 + 512 + h * 64 + col0;
        bh16* op = aout + (ll)b * (NVEC * 512) + nrow * 512 + h * 64 + col0;
        typedef __attribute__((ext_vector_type(4))) __bf16 bf16x4;
        bf16x4 c0 = *(const bf16x4*)cv;
        bf16x4 o0;
#pragma unroll
        for (int j = 0; j < 4; ++j)
            o0[j] = (bh16)(red[row * RPITCH + col0 + j] + (float)c0[j]);
        *(bf16x4*)op = o0;
    }
}

// ===========================================================================
// Small kernels
// ===========================================================================
__global__ void embed_k(const float* __restrict__ x, const float* __restrict__ w,
                        const float* __restrict__ b, float* __restrict__ h)
{
    ll idx = (ll)blockIdx.x * 256 + threadIdx.x;
    int d = (int)(idx & 511);
    ll bn = idx >> 9;
    h[idx] = x[bn * 2] * w[d] + x[bn * 2 + 1] * w[512 + d] + b[d];
}

__global__ void __launch_bounds__(256)
ln_k(const float* __restrict__ X, const float* __restrict__ g,
     const float* __restrict__ bta, bh16* __restrict__ Y)
{
    const ll row = blockIdx.x;
    const float* x = X + row * 512;
    bh16* y = Y + row * 512;
    const int tid = threadIdx.x;
    float v0 = x[tid], v1 = x[tid + 256];
    float s = v0 + v1;
    float q = v0 * v0 + v1 * v1;
    __shared__ float sred[8];
    for (int o = 32; o; o >>= 1) { s += __shfl_down(s, o); q += __shfl_down(q, o); }
    const int lane = tid & 63, w = tid >> 6;
    if (lane == 0) { sred[w] = s; sred[4 + w] = q; }
    __syncthreads();
    float ssum = sred[0] + sred[1] + sred[2] + sred[3];
    float qsum = sred[4] + sred[5] + sred[6] + sred[7];
    float mu = ssum * (1.0f / 512.0f);
    float var = qsum * (1.0f / 512.0f) - mu * mu;
    float r = rsqrtf(var + 1e-5f);
    y[tid] = (bh16)((v0 - mu) * r * g[tid] + bta[tid]);
    y[tid + 256] = (bh16)((v1 - mu) * r * g[tid + 256] + bta[tid + 256]);
}

__global__ void __launch_bounds__(256)
cvtT_k(const float* __restrict__ in, bh16* __restrict__ outp, int C, int R)
{
    __shared__ float t[64][65];
    const int nCt = C >> 6;
    const int c0 = (blockIdx.x % nCt) * 64;
    const int r0 = (blockIdx.x / nCt) * 64;
    const int tid = threadIdx.x;
#pragma unroll
    for (int j = 0; j < 16; ++j) {
        int idx = j * 256 + tid;
        int lr = idx >> 6, lc = idx & 63;
        t[lc][lr] = in[(ll)(r0 + lr) * C + c0 + lc];
    }
    __syncthreads();
#pragma unroll
    for (int v = 0; v < 2; ++v) {
        int flat = v * 256 + tid;
        int lc = flat >> 3, r8 = (flat & 7) * 8;
        bf16x8 o;
#pragma unroll
        for (int j = 0; j < 8; ++j) o[j] = (bh16)t[lc][r8 + j];
        *(bf16x8*)(outp + (ll)(c0 + lc) * R + r0 + r8) = o;
    }
}

__global__ void landmarks_k(const bh16* __restrict__ qkv,
                            bh16* __restrict__ qlb, bh16* __restrict__ klb)
{
    int idx = blockIdx.x * 256 + threadIdx.x;
    int d = idx & 63;
    int m = (idx >> 6) & 255;
    int h = (idx >> 14) & 7;
    int b = idx >> 17;
    const bh16* base = qkv + (ll)b * (NVEC * 1536) + (ll)(m * LSEG) * 1536 + h * 64 + d;
    float sq = 0.f, sk = 0.f;
#pragma unroll
    for (int l = 0; l < LSEG; ++l) {
        sq += (float)base[(ll)l * 1536];
        sk += (float)base[(ll)l * 1536 + 512];
    }
    ll o = (ll)(b * 8 + h) * 16384 + m * 64 + d;
    qlb[o] = (bh16)(sq * (0.0625f * 0.125f));
    klb[o] = (bh16)(sk * 0.0625f);
}

__global__ void wbt_k(const bh16* __restrict__ wb, bh16* __restrict__ wbt)
{
    int idx = blockIdx.x * 256 + threadIdx.x;
    int d = idx & 63, kg = (idx >> 6) & 31, bhh = idx >> 11;
    const bh16* p = wb + (ll)bhh * 16384 + kg * 8 * 64 + d;
    bf16x8 o;
#pragma unroll
    for (int j = 0; j < 8; ++j) o[j] = p[j * 64];
    *(bf16x8*)(wbt + (ll)bhh * 16384 + d * 256 + kg * 8) = o;
}

// reduce split-K partials for a 2-sample chunk:
// part [2][8h][8s][256][64] f32 -> A3Vb bf16 at [bh0+smp*8+h][256][64]
__global__ void a3vred_k(const float* __restrict__ part, bh16* __restrict__ outp)
{
    int idx = blockIdx.x * 256 + threadIdx.x;   // 262144
    int smp = idx >> 17;
    int rest = idx & 131071;
    int h = rest >> 14, o = rest & 16383;
    const float* p = part + (ll)smp * 1048576 + (ll)h * 131072 + o;
    float s = 0.f;
#pragma unroll
    for (int j = 0; j < 8; ++j) s += p[j * 16384];
    outp[(ll)(smp * 8 + h) * 16384 + o] = (bh16)s;
}

__global__ void __launch_bounds__(256)
conv_k(bh16* __restrict__ qkv, const float* __restrict__ cw)
{
    int idx = blockIdx.x * 256 + threadIdx.x;
    int c8 = idx & 63;
    int ng = (idx >> 6) & 1023;
    int b  = idx >> 16;
    const int n0 = ng * 4;
    const int h = c8 >> 3;
    const bh16* v = qkv + (ll)b * (NVEC * 1536) + 1024 + c8 * 8;

    float wreg[KER];
#pragma unroll
    for (int k = 0; k < KER; ++k) wreg[k] = cw[h * KER + k];

    float acc[4][8];
#pragma unroll
    for (int t = 0; t < 4; ++t)
#pragma unroll
        for (int e = 0; e < 8; ++e) acc[t][e] = 0.f;

#pragma unroll
    for (int m = 0; m < 36; ++m) {
        int nn = n0 + m - (KER / 2);
        bf16x8 vv = {};
        if ((unsigned)nn < (unsigned)NVEC)
            vv = *(const bf16x8*)(v + (ll)nn * 1536);
#pragma unroll
        for (int t = 0; t < 4; ++t) {
            constexpr int KMAX = KER - 1;
            int k = m - t;
            if (k >= 0 && k <= KMAX) {
                float wk = wreg[k];
#pragma unroll
                for (int e = 0; e < 8; ++e)
                    acc[t][e] = fmaf((float)vv[e], wk, acc[t][e]);
            }
        }
    }

    bh16* o = qkv + (ll)b * (NVEC * 1536) + (ll)n0 * 1536 + 512 + c8 * 8;
#pragma unroll
    for (int t = 0; t < 4; ++t) {
        bf16x8 ov;
#pragma unroll
        for (int e = 0; e < 8; ++e) ov[e] = (bh16)acc[t][e];
        *(bf16x8*)(o + (ll)t * 1536) = ov;
    }
}

__device__ __forceinline__ float blkmax(float m, float* red, int tid)
{
#pragma unroll
    for (int o = 32; o; o >>= 1) m = fmaxf(m, __shfl_down(m, o));
    if ((tid & 63) == 0) red[tid >> 6] = m;
    __syncthreads();
    m = fmaxf(fmaxf(red[0], red[1]), fmaxf(red[2], red[3]));
    __syncthreads();
    return m;
}
__device__ __forceinline__ float blksum(float s, float* red, int tid)
{
#pragma unroll
    for (int o = 32; o; o >>= 1) s += __shfl_down(s, o);
    if ((tid & 63) == 0) red[tid >> 6] = s;
    __syncthreads();
    s = red[0] + red[1] + red[2] + red[3];
    __syncthreads();
    return s;
}

// in-place bf16 row softmax, L == 4096; one block (256 thr) per row
__global__ void __launch_bounds__(256)
softmax_bf_k(bh16* __restrict__ X, int L)
{
    const ll row = blockIdx.x;
    bh16* x = X + row * (ll)L;
    const int tid = threadIdx.x;
    __shared__ float red[4];
    float v[16];
    bf16x8 a = *(const bf16x8*)(x + tid * 8);
    bf16x8 b = *(const bf16x8*)(x + 2048 + tid * 8);
#pragma unroll
    for (int j = 0; j < 8; ++j) { v[j] = (float)a[j]; v[8 + j] = (float)b[j]; }
    float m = -1e30f;
#pragma unroll
    for (int j = 0; j < 16; ++j) m = fmaxf(m, v[j]);
    m = blkmax(m, red, tid);
    float s = 0.f;
#pragma unroll
    for (int j = 0; j < 16; ++j) { v[j] = __expf(v[j] - m); s += v[j]; }
    s = blksum(s, red, tid);
    float inv = 1.0f / s;
    bf16x8 oa, ob;
#pragma unroll
    for (int j = 0; j < 8; ++j) { oa[j] = (bh16)(v[j] * inv); ob[j] = (bh16)(v[8 + j] * inv); }
    *(bf16x8*)(x + tid * 8) = oa;
    *(bf16x8*)(x + 2048 + tid * 8) = ob;
}

__global__ void __launch_bounds__(256)
pinv_init_k(const bh16* __restrict__ X, bh16* __restrict__ Z)
{
    const ll bh = blockIdx.x;
    const bh16* x = X + bh * 65536;
    bh16* z = Z + bh * 65536;
    const int tid = threadIdx.x;
    float rs = 0.f, cs = 0.f;
    for (int j = 0; j < 256; ++j) {
        rs += fabsf((float)x[tid * 256 + j]);
        cs += fabsf((float)x[j * 256 + tid]);
    }
    __shared__ float rbuf[256], cbuf[256];
    rbuf[tid] = rs; cbuf[tid] = cs;
    __syncthreads();
    for (int o = 128; o; o >>= 1) {
        if (tid < o) {
            rbuf[tid] = fmaxf(rbuf[tid], rbuf[tid + o]);
            cbuf[tid] = fmaxf(cbuf[tid], cbuf[tid + o]);
        }
        __syncthreads();
    }
    float inv = 1.0f / (rbuf[0] * cbuf[0]);
    for (int e = tid; e < 65536; e += 256) {
        int i = e >> 8, j = e & 255;
        z[e] = (bh16)((float)x[j * 256 + i] * inv);
    }
}

__global__ void final_init_k(const float* __restrict__ fb, float* __restrict__ out)
{
    int i = threadIdx.x;
    if (i < BB_ * NCLASS) out[i] = fb[i % NCLASS];
}

__global__ void __launch_bounds__(256)
final_gemv_k(const float* __restrict__ hbuf, const float* __restrict__ w,
             float* __restrict__ out)
{
    const int half = blockIdx.y;
    const int chunk = blockIdx.x;
    const int tid = threadIdx.x;
    const int k0 = chunk * 8192;
    float pc[4][NCLASS] = {};
    for (int e = 0; e < 32; ++e) {
        int k = k0 + e * 256 + tid;
        const float* wr = w + (ll)k * NCLASS;
        float wv[NCLASS];
#pragma unroll
        for (int c = 0; c < NCLASS; ++c) wv[c] = wr[c];
#pragma unroll
        for (int b = 0; b < 4; ++b) {
            float hv = hbuf[(ll)(half * 4 + b) * (NVEC * DIM) + k];
#pragma unroll
            for (int c = 0; c < NCLASS; ++c) pc[b][c] = fmaf(hv, wv[c], pc[b][c]);
        }
    }
    __shared__ float red[4][4][NCLASS];
    const int lane = tid & 63, wv_ = tid >> 6;
#pragma unroll
    for (int b = 0; b < 4; ++b)
#pragma unroll
        for (int c = 0; c < NCLASS; ++c) {
            float s = pc[b][c];
#pragma unroll
            for (int o = 32; o; o >>= 1) s += __shfl_down(s, o);
            if (lane == 0) red[wv_][b][c] = s;
        }
    __syncthreads();
    if (tid < 4 * NCLASS) {
        int b = tid / NCLASS, c = tid % NCLASS;
        float s = red[0][b][c] + red[1][b][c] + red[2][b][c] + red[3][b][c];
        atomicAdd(out + (half * 4 + b) * NCLASS + c, s);
    }
}

// ===========================================================================
extern "C" void kernel_launch(void* const* d_in, const int* in_sizes, int n_in,
                              void* d_out, int out_size, void* d_ws, size_t ws_size,
                              hipStream_t stream)
{
    const float* x      = (const float*)d_in[0];
    const float* lin_w  = (const float*)d_in[1];
    const float* lin_b  = (const float*)d_in[2];
    const float* ln1_g  = (const float*)d_in[3];
    const float* ln1_b  = (const float*)d_in[4];
    const float* qkv_w  = (const float*)d_in[5];
    const float* out_w  = (const float*)d_in[6];
    const float* out_b  = (const float*)d_in[7];
    const float* conv_w = (const float*)d_in[8];
    const float* ln2_g  = (const float*)d_in[9];
    const float* ln2_b  = (const float*)d_in[10];
    const float* ff1_w  = (const float*)d_in[11];
    const float* ff1_b  = (const float*)d_in[12];
    const float* ff2_w  = (const float*)d_in[13];
    const float* ff2_b  = (const float*)d_in[14];
    const float* final_w = (const float*)d_in[15];
    const float* final_b = (const float*)d_in[16];
    float* out = (float*)d_out;
    float* ws  = (float*)d_ws;

    // ---- workspace layout (f32 units), total 56,623,104 f32 = 226.5 MB ----
    float* H    = ws;                                  // [8][4096][512] f32
    bh16*  QKV  = (bh16*)(ws + 16777216);              // [8][4096][1536] bf16
    float* P    = ws + 41943040;                       // pool, 10,485,760 f32
    bh16*  qlbf = (bh16*)(ws + 52428800);              // [64bh][256][64] bf16
    bh16*  klbf = (bh16*)(ws + 52953088);
    bh16*  A3Vb = (bh16*)(ws + 53477376);              // [64bh][256][64] bf16
    bh16*  WBb  = (bh16*)(ws + 54001664);
    bh16*  WBT  = (bh16*)(ws + 54525952);              // [64bh][64][256] bf16
    bh16*  WQT  = (bh16*)(ws + 55050240);              // [1536][512] bf16
    bh16*  WOT  = (bh16*)(ws + 55443456);              // [512][512] bf16
    bh16*  F1WT = (bh16*)(ws + 55574528);              // [2048][512] bf16
    bh16*  F2WT = (bh16*)(ws + 56098816);              // [512][2048] bf16
    if (ws_size < 56623104ULL * 4) return;

    // pool aliases (time-sliced)
    bh16*  XLNall = (bh16*)P;                          // [32768][512] bf16
    bh16*  ATT3c  = (bh16*)P;                          // [16bh][256][4096] bf16
    float* A3Vp   = P + 8388608;                       // [2][8h][8s][256][64] f32
    bh16*  Xbf = (bh16*)P;                             // pinv: 5 x [64][256][256] bf16
    bh16*  Z0  = (bh16*)(P + 2097152);
    bh16*  Z1  = (bh16*)(P + 4194304);
    bh16*  T1  = (bh16*)(P + 6291456);
    bh16*  T2  = (bh16*)(P + 8388608);
    bh16*  AOUTa  = (bh16*)P;                          // [8][4096][512] bf16
    bh16*  XLNc   = (bh16*)P;                          // FFN: [8192][512] bf16
    bh16*  HIDc   = (bh16*)(P + 2097152);              // [2][4096][2048] bf16

    const ll SMP = (ll)NVEC * 1536;

    hipLaunchKernelGGL(embed_k, dim3(65536), dim3(256), 0, stream, x, lin_w, lin_b, H);

    for (int i = 0; i < DEPTH; ++i) {
        const float* wq  = qkv_w + (ll)i * 512 * 1536;
        const float* wo  = out_w + (ll)i * 512 * 512;
        const float* bo  = out_b + (ll)i * 512;
        const float* cw  = conv_w + (ll)i * HEADS * KER;
        const float* g1  = ln1_g + (ll)i * 512;
        const float* b1  = ln1_b + (ll)i * 512;
        const float* g2  = ln2_g + (ll)i * 512;
        const float* b2  = ln2_b + (ll)i * 512;
        const float* f1w = ff1_w + (ll)i * 512 * 2048;
        const float* f1b = ff1_b + (ll)i * 2048;
        const float* f2w = ff2_w + (ll)i * 2048 * 512;
        const float* f2b = ff2_b + (ll)i * 512;

        hipLaunchKernelGGL(cvtT_k, dim3(192), dim3(256), 0, stream, wq, WQT, 1536, 512);
        hipLaunchKernelGGL(cvtT_k, dim3(64), dim3(256), 0, stream, wo, WOT, 512, 512);
        hipLaunchKernelGGL(cvtT_k, dim3(256), dim3(256), 0, stream, f1w, F1WT, 2048, 512);
        hipLaunchKernelGGL(cvtT_k, dim3(256), dim3(256), 0, stream, f2w, F2WT, 512, 2048);

        // LN1 + qkv (M=32768)
        hipLaunchKernelGGL(ln_k, dim3(32768), dim3(256), 0, stream, H, g1, b1, XLNall);
        mg<2,2,0,0,0,1,0,0>(stream, 32768, 1536, 512, XLNall, 512, WQT, 512,
            QKV, 1536, nullptr, nullptr, 1, 1, 0,0, 0,0, 0,0, 1.f, 0.f);

        hipLaunchKernelGGL(landmarks_k, dim3(4096), dim3(256), 0, stream, QKV, qlbf, klbf);

        // ---- attn3 / softmax / a3v in 2-sample chunks (bf16 scores) ----
        for (int c = 0; c < 4; ++c) {
            const bh16* qkvc = QKV + (ll)c * 2 * SMP;
            mg<2,2,0,0,0,1,0,0>(stream, 256, 4096, 64,
                qlbf + (ll)c * 262144, 64, qkvc + 512, 1536,
                ATT3c, 4096, nullptr, nullptr, 16, 8,
                131072, 16384, SMP, 64, 8388608LL, 1048576, 1.f, 0.f);
            hipLaunchKernelGGL(softmax_bf_k, dim3(4096), dim3(256), 0, stream, ATT3c, 4096);
            for (int s = 0; s < 2; ++s) {
                mg<4,1,1,0,0,0,0,0>(stream, 256, 64, 512,
                    ATT3c + (ll)s * 8 * 1048576, 4096, qkvc + (ll)s * SMP + 1024, 1536,
                    A3Vp + (ll)s * 1048576, 64, nullptr, nullptr, 64, 8,
                    1048576, 512, 64, 512LL * 1536, 131072, 16384, 1.f, 0.f);
            }
            hipLaunchKernelGGL(a3vred_k, dim3(1024), dim3(256), 0, stream,
                               A3Vp, A3Vb + (ll)c * 2 * 131072);
        }

        // conv -> QKV k-slot (k fully consumed above)
        hipLaunchKernelGGL(conv_k, dim3(2048), dim3(256), 0, stream, QKV, cw);

        // ---- pinv (bf16 MFMA, batched 64); X via fused-softmax GEMM ----
        mg<1,4,0,0,0,1,0,1>(stream, 256, 256, 64, qlbf, 64, klbf, 64,
            Xbf, 256, nullptr, nullptr, 64, 64, 0, 16384, 0, 16384, 0, 65536, 1.f, 0.f);
        hipLaunchKernelGGL(pinv_init_k, dim3(64), dim3(256), 0, stream, Xbf, Z0);
        bh16* zc = Z0; bh16* zn = Z1;
        for (int it = 0; it < ITERS; ++it) {
            mg<2,2,1,0,0,1,1,0>(stream, 256, 256, 256, Xbf, 256, zc, 256,
                T1, 256, T2, nullptr, 64, 64, 0, 65536, 0, 65536, 0, 65536, 1.f, 7.f);
            mg<2,2,1,0,0,1,0,0>(stream, 256, 256, 256, T1, 256, T2, 256,
                zn, 256, nullptr, nullptr, 64, 64, 0, 65536, 0, 65536, 0, 65536, -1.f, 15.f);
            mg<2,2,1,0,0,1,0,0>(stream, 256, 256, 256, T1, 256, zn, 256,
                T2, 256, nullptr, nullptr, 64, 64, 0, 65536, 0, 65536, 0, 65536, -1.f, 13.f);
            mg<2,2,1,0,0,1,0,0>(stream, 256, 256, 256, zc, 256, T2, 256,
                zn, 256, nullptr, nullptr, 64, 64, 0, 65536, 0, 65536, 0, 65536, 0.25f, 0.f);
            bh16* t = zc; zc = zn; zn = t;
        }
        mg<4,1,1,0,0,1,0,0>(stream, 256, 64, 256, zc, 256, A3Vb, 64,
            WBb, 64, nullptr, nullptr, 64, 64, 0, 65536, 0, 16384, 0, 16384, 1.f, 0.f);
        hipLaunchKernelGGL(wbt_k, dim3(512), dim3(256), 0, stream, WBb, WBT);

        // ---- fused attn1 + P@wb + conv -> AOUTa; then one out-proj ----
        hipLaunchKernelGGL(fattn_k, dim3(256, 64), dim3(256), 0, stream,
                           QKV, klbf, WBT, AOUTa);
        mg<2,2,0,0,1,0,0,0>(stream, 32768, 512, 512, AOUTa, 512, WOT, 512,
            H, 512, nullptr, bo, 1, 1, 0,0, 0,0, 0,0, 1.f, 0.f);

        // ---- FFN in 2-sample chunks ----
        for (int c = 0; c < 4; ++c) {
            float* Hc = H + (ll)c * 2 * 2097152;
            hipLaunchKernelGGL(ln_k, dim3(8192), dim3(256), 0, stream, Hc, g2, b2, XLNc);
            mg<2,2,0,1,0,1,0,0>(stream, 8192, 2048, 512, XLNc, 512, F1WT, 512,
                HIDc, 2048, nullptr, f1b, 1, 1, 0,0, 0,0, 0,0, 1.f, 0.f);
            mg<2,2,0,0,1,0,0,0>(stream, 8192, 512, 2048, HIDc, 2048, F2WT, 2048,
                Hc, 512, nullptr, f2b, 1, 1, 0,0, 0,0, 0,0, 1.f, 0.f);
        }
    }

    hipLaunchKernelGGL(final_init_k, dim3(1), dim3(128), 0, stream, final_b, out);
    hipLaunchKernelGGL(final_gemv_k, dim3(256, 2), dim3(256), 0, stream, H, final_w, out);
}

// Round 20
// 3145.988 us; speedup vs baseline: 1.0281x; 1.0281x over previous
//
#include <hip/hip_runtime.h>
#include <hip/hip_bf16.h>

// Problem constants
#define BB_ 8
#define NVEC 4096
#define DIM 512
#define HEADS 8
#define DH 64
#define MM_ 256
#define ITERS 6
#define DEPTH 2
#define NCLASS 10
#define KER 33
#define INNER 512
#define LSEG 16  // NVEC / MM_

typedef long long ll;
typedef __bf16 bh16;
typedef __attribute__((ext_vector_type(8))) __bf16 bf16x8;
typedef __attribute__((ext_vector_type(4))) float f32x4;

// ===========================================================================
// MFMA bf16 GEMM. TRB=0 (TN): C = A[M,K] @ B_t[N,K]^T. TRB=1 (NN).
// Tile BM=WR*64 x BN=WC*64, BK=32, 256 threads = 4 waves (WR*WC==4).
// XCD-bijective block swizzle (m204). SMAX: fused row-softmax (WR==1,
// gridDim.x==1). DUAL: C=acc, C2=diagv*I-acc. Batch: z -> bo=z/BI, bi=z%BI.
// ===========================================================================
template<int WR, int WC, bool TRB, bool GELU_ACT, bool RESID, bool BF16OUT,
         bool DUAL, bool SMAX>
__global__ void __launch_bounds__(256)
mgemm_k(const bh16* __restrict__ A, const bh16* __restrict__ B,
        const float* __restrict__ bias, void* __restrict__ Cv, void* __restrict__ C2v,
        int K, int lda, int ldb, int ldc,
        int BI, ll sAo, ll sAi, ll sBo, ll sBi, ll sCo, ll sCi,
        float alpha, float diagv)
{
    constexpr int BM = WR * 64, BN = WC * 64;
    const int bz = blockIdx.z;
    const int bo = bz / BI, bi = bz % BI;
    const bh16* Ab = A + bo * sAo + (ll)bi * sAi;
    const bh16* Bb = B + bo * sBo + (ll)bi * sBi;
    const ll coff = bo * sCo + (ll)bi * sCi;

    const int gx = gridDim.x;
    const int nwg = gx * gridDim.y;
    int flat = blockIdx.y * gx + blockIdx.x;
    {
        int xcd = flat & 7, base = flat >> 3;
        int q = nwg >> 3, rr = nwg & 7;
        flat = (xcd < rr ? xcd * (q + 1) : rr * (q + 1) + (xcd - rr) * q) + base;
    }
    const int m0 = (flat / gx) * BM;
    const int n0 = (flat % gx) * BN;

    const int tid = threadIdx.x;
    const int lane = tid & 63;
    const int wave = tid >> 6;
    const int wr = wave / WC, wc = wave % WC;

    __shared__ bh16 Al[BM * 32];
    __shared__ bh16 Bl[BN * 32];
    __shared__ float srow[SMAX ? 4 * 64 : 4];

    f32x4 acc[4][4];
#pragma unroll
    for (int i = 0; i < 4; ++i)
#pragma unroll
        for (int j = 0; j < 4; ++j) acc[i][j] = (f32x4){0.f, 0.f, 0.f, 0.f};

    const int srowi = tid >> 2;  // 0..63
    const int ssl   = tid & 3;   // 16B slot (linear LDS dest)

    const int rsel  = ((lane & 15) >> 1) & 3;
    const int kslot = lane >> 4;

    for (int k0 = 0; k0 < K; k0 += 32) {
        __syncthreads();
#pragma unroll
        for (int i = 0; i < BM / 64; ++i) {
            int row = i * 64 + srowi;
            int gsl = ssl ^ ((row >> 1) & 3);
            __builtin_amdgcn_global_load_lds(
                (const __attribute__((address_space(1))) unsigned int*)
                    (Ab + (ll)(m0 + row) * lda + k0 + gsl * 8),
                (__attribute__((address_space(3))) unsigned int*)
                    (Al + row * 32 + ssl * 8),
                16, 0, 0);
        }
        if (!TRB) {
#pragma unroll
            for (int i = 0; i < BN / 64; ++i) {
                int row = i * 64 + srowi;
                int gsl = ssl ^ ((row >> 1) & 3);
                __builtin_amdgcn_global_load_lds(
                    (const __attribute__((address_space(1))) unsigned int*)
                        (Bb + (ll)(n0 + row) * ldb + k0 + gsl * 8),
                    (__attribute__((address_space(3))) unsigned int*)
                        (Bl + row * 32 + ssl * 8),
                    16, 0, 0);
            }
        } else {
            const int bk = tid >> 3;
            const int nb0 = (tid & 7) * (BN / 8);
#pragma unroll
            for (int v8 = 0; v8 < BN / 64; ++v8) {
                int nb = nb0 + v8 * 8;
                bf16x8 v = *(const bf16x8*)(Bb + (ll)(k0 + bk) * ldb + n0 + nb);
#pragma unroll
                for (int j = 0; j < 8; ++j) {
                    int n = nb + j;
                    int sl = (bk >> 3) ^ ((n >> 1) & 3);
                    Bl[n * 32 + sl * 8 + (bk & 7)] = v[j];
                }
            }
        }
        __syncthreads();

        bf16x8 af[4], bfr[4];
#pragma unroll
        for (int mi = 0; mi < 4; ++mi) {
            int row = wr * 64 + mi * 16 + (lane & 15);
            af[mi] = *(const bf16x8*)(Al + row * 32 + (kslot ^ rsel) * 8);
        }
#pragma unroll
        for (int ni = 0; ni < 4; ++ni) {
            int row = wc * 64 + ni * 16 + (lane & 15);
            bfr[ni] = *(const bf16x8*)(Bl + row * 32 + (kslot ^ rsel) * 8);
        }
#pragma unroll
        for (int mi = 0; mi < 4; ++mi)
#pragma unroll
            for (int ni = 0; ni < 4; ++ni)
                acc[mi][ni] = __builtin_amdgcn_mfma_f32_16x16x32_bf16(
                    af[mi], bfr[ni], acc[mi][ni], 0, 0, 0);
    }

    if (SMAX) {
        bh16* Cb = (bh16*)Cv;
#pragma unroll
        for (int mi = 0; mi < 4; ++mi)
#pragma unroll
            for (int ni = 0; ni < 4; ++ni)
#pragma unroll
                for (int r = 0; r < 4; ++r) acc[mi][ni][r] *= alpha;
        float mx[4][4];
#pragma unroll
        for (int mi = 0; mi < 4; ++mi)
#pragma unroll
            for (int r = 0; r < 4; ++r) {
                float m_ = acc[mi][0][r];
#pragma unroll
                for (int ni = 1; ni < 4; ++ni) m_ = fmaxf(m_, acc[mi][ni][r]);
#pragma unroll
                for (int msk = 1; msk < 16; msk <<= 1)
                    m_ = fmaxf(m_, __shfl_xor(m_, msk));
                mx[mi][r] = m_;
            }
        if ((lane & 15) == 0) {
#pragma unroll
            for (int mi = 0; mi < 4; ++mi)
#pragma unroll
                for (int r = 0; r < 4; ++r)
                    srow[wc * 64 + mi * 16 + (lane >> 4) * 4 + r] = mx[mi][r];
        }
        __syncthreads();
        float M_[4][4];
#pragma unroll
        for (int mi = 0; mi < 4; ++mi)
#pragma unroll
            for (int r = 0; r < 4; ++r) {
                int row = mi * 16 + (lane >> 4) * 4 + r;
                M_[mi][r] = fmaxf(fmaxf(srow[row], srow[64 + row]),
                                  fmaxf(srow[128 + row], srow[192 + row]));
            }
        __syncthreads();
        float sm[4][4];
#pragma unroll
        for (int mi = 0; mi < 4; ++mi)
#pragma unroll
            for (int r = 0; r < 4; ++r) {
                float s_ = 0.f;
#pragma unroll
                for (int ni = 0; ni < 4; ++ni) {
                    float e = __expf(acc[mi][ni][r] - M_[mi][r]);
                    acc[mi][ni][r] = e;
                    s_ += e;
                }
#pragma unroll
                for (int msk = 1; msk < 16; msk <<= 1)
                    s_ += __shfl_xor(s_, msk);
                sm[mi][r] = s_;
            }
        if ((lane & 15) == 0) {
#pragma unroll
            for (int mi = 0; mi < 4; ++mi)
#pragma unroll
                for (int r = 0; r < 4; ++r)
                    srow[wc * 64 + mi * 16 + (lane >> 4) * 4 + r] = sm[mi][r];
        }
        __syncthreads();
#pragma unroll
        for (int mi = 0; mi < 4; ++mi)
#pragma unroll
            for (int r = 0; r < 4; ++r) {
                int row = mi * 16 + (lane >> 4) * 4 + r;
                float inv = 1.0f / (srow[row] + srow[64 + row] +
                                    srow[128 + row] + srow[192 + row]);
                int rowg = m0 + row;
#pragma unroll
                for (int ni = 0; ni < 4; ++ni) {
                    int colg = n0 + wc * 64 + ni * 16 + (lane & 15);
                    Cb[coff + (ll)rowg * ldc + colg] = (bh16)(acc[mi][ni][r] * inv);
                }
            }
        return;
    }

#pragma unroll
    for (int mi = 0; mi < 4; ++mi) {
#pragma unroll
        for (int ni = 0; ni < 4; ++ni) {
            const int colg = n0 + wc * 64 + ni * 16 + (lane & 15);
            const float bia = (!DUAL && bias) ? bias[colg] : 0.f;
#pragma unroll
            for (int r = 0; r < 4; ++r) {
                const int rowg = m0 + wr * 64 + mi * 16 + (lane >> 4) * 4 + r;
                const float a = acc[mi][ni][r];
                const ll off = coff + (ll)rowg * ldc + colg;
                if (DUAL) {
                    ((bh16*)Cv)[off] = (bh16)a;
                    float w = ((rowg == colg) ? diagv : 0.f) - a;
                    ((bh16*)C2v)[off] = (bh16)w;
                } else {
                    float v = alpha * a + bia;
                    if (diagv != 0.f && rowg == colg) v += diagv;
                    if (GELU_ACT) {
                        float t = tanhf(0.7978845608f * (v + 0.044715f * v * v * v));
                        v = 0.5f * v * (1.0f + t);
                    }
                    if (BF16OUT) {
                        ((bh16*)Cv)[off] = (bh16)v;
                    } else {
                        float* p = (float*)Cv + off;
                        float o = v;
                        if (RESID) o += *p;
                        *p = o;
                    }
                }
            }
        }
    }
}

template<int WR, int WC, bool TRB, bool G, bool R, bool BO, bool D, bool SX>
static inline void mg(hipStream_t s, int M, int N, int K,
                      const bh16* A, int lda, const bh16* B, int ldb,
                      void* C, int ldc, void* C2, const float* bias,
                      int batch, int BI,
                      ll sAo, ll sAi, ll sBo, ll sBi, ll sCo, ll sCi,
                      float alpha, float diagv)
{
    dim3 grid(N / (WC * 64), M / (WR * 64), batch);
    hipLaunchKernelGGL((mgemm_k<WR, WC, TRB, G, R, BO, D, SX>), grid, dim3(256), 0, s,
                       A, B, bias, C, C2, K, lda, ldb, ldc, BI,
                       sAo, sAi, sBo, sBi, sCo, sCi, alpha, diagv);
}

// ===========================================================================
// Fused attn1. Block = (32 q-rows, one (b,h)) -- measured-optimal q-block
// (TLP sweep: QB64=114us, QB32=99us, QB16=146us). Per-row math BIT-IDENTICAL
// across QB variants (same MFMA chains, softmax tree, rounding sites).
// Phase 1: S=q@kl^T (K=64), cross-wave softmax (alpha 0.125), P -> LDS
//   (pitch 264, linear). Phase 2: wave-K-split + f32 LDS reduce (pitch 68)
//   aliased over Pl (barrier-separated). Vectorized bf16x8 epilogue + conv.
// ===========================================================================
#define QB_ROWS 32
#define PPITCH 264
#define RPITCH 68
__global__ void __launch_bounds__(256)
fattn_k(const bh16* __restrict__ qkv, const bh16* __restrict__ klb,
        const bh16* __restrict__ wbt, bh16* __restrict__ aout)
{
    const int qb = blockIdx.x;          // 0..127
    const int bh = blockIdx.y;          // 0..63
    const int b = bh >> 3, h = bh & 7;
    const int q0 = qb * QB_ROWS;
    const int tid = threadIdx.x, lane = tid & 63, wave = tid >> 6;
    const ll SMPq = (ll)NVEC * 1536;

    __shared__ __align__(16) char smem[QB_ROWS * PPITCH * 2];  // 16,896 B
    bh16*  Pl  = (bh16*)smem;                                  // phase 1-2a
    float* red = (float*)smem;                                 // phase 2b (aliased)
    __shared__ float srow[4 * QB_ROWS];                        // 512 B

    const bh16* qbase = qkv + (ll)b * SMPq + (ll)q0 * 1536 + h * 64;
    const bh16* klbh = klb + (ll)bh * 16384;
    const bh16* wbh  = wbt + (ll)bh * 16384;

    const int kslot = lane >> 4;

    // ---- phase 1: scores (wave covers cols wave*64..wave*64+63) ----
    f32x4 acc[2][4];
#pragma unroll
    for (int i = 0; i < 2; ++i)
#pragma unroll
        for (int j = 0; j < 4; ++j) acc[i][j] = (f32x4){0.f, 0.f, 0.f, 0.f};
#pragma unroll
    for (int ks = 0; ks < 2; ++ks) {
        int k0 = ks * 32;
        bf16x8 af[2], bfr[4];
#pragma unroll
        for (int mi = 0; mi < 2; ++mi) {
            int row = mi * 16 + (lane & 15);
            af[mi] = *(const bf16x8*)(qbase + (ll)row * 1536 + k0 + kslot * 8);
        }
#pragma unroll
        for (int ni = 0; ni < 4; ++ni) {
            int brow = wave * 64 + ni * 16 + (lane & 15);
            bfr[ni] = *(const bf16x8*)(klbh + brow * 64 + k0 + kslot * 8);
        }
#pragma unroll
        for (int mi = 0; mi < 2; ++mi)
#pragma unroll
            for (int ni = 0; ni < 4; ++ni)
                acc[mi][ni] = __builtin_amdgcn_mfma_f32_16x16x32_bf16(
                    af[mi], bfr[ni], acc[mi][ni], 0, 0, 0);
    }

    // ---- softmax over 256 cols (4 wave-quadrants) ----
#pragma unroll
    for (int mi = 0; mi < 2; ++mi)
#pragma unroll
        for (int ni = 0; ni < 4; ++ni)
#pragma unroll
            for (int r = 0; r < 4; ++r) acc[mi][ni][r] *= 0.125f;
    float mx[2][4];
#pragma unroll
    for (int mi = 0; mi < 2; ++mi)
#pragma unroll
        for (int r = 0; r < 4; ++r) {
            float m_ = acc[mi][0][r];
#pragma unroll
            for (int ni = 1; ni < 4; ++ni) m_ = fmaxf(m_, acc[mi][ni][r]);
#pragma unroll
            for (int msk = 1; msk < 16; msk <<= 1)
                m_ = fmaxf(m_, __shfl_xor(m_, msk));
            mx[mi][r] = m_;
        }
    if ((lane & 15) == 0) {
#pragma unroll
        for (int mi = 0; mi < 2; ++mi)
#pragma unroll
            for (int r = 0; r < 4; ++r)
                srow[wave * QB_ROWS + mi * 16 + (lane >> 4) * 4 + r] = mx[mi][r];
    }
    __syncthreads();
    float M_[2][4];
#pragma unroll
    for (int mi = 0; mi < 2; ++mi)
#pragma unroll
        for (int r = 0; r < 4; ++r) {
            int row = mi * 16 + (lane >> 4) * 4 + r;
            M_[mi][r] = fmaxf(fmaxf(srow[row], srow[QB_ROWS + row]),
                              fmaxf(srow[2 * QB_ROWS + row], srow[3 * QB_ROWS + row]));
        }
    __syncthreads();
    float sm[2][4];
#pragma unroll
    for (int mi = 0; mi < 2; ++mi)
#pragma unroll
        for (int r = 0; r < 4; ++r) {
            float s_ = 0.f;
#pragma unroll
            for (int ni = 0; ni < 4; ++ni) {
                float e = __expf(acc[mi][ni][r] - M_[mi][r]);
                acc[mi][ni][r] = e;
                s_ += e;
            }
#pragma unroll
            for (int msk = 1; msk < 16; msk <<= 1)
                s_ += __shfl_xor(s_, msk);
            sm[mi][r] = s_;
        }
    if ((lane & 15) == 0) {
#pragma unroll
        for (int mi = 0; mi < 2; ++mi)
#pragma unroll
            for (int r = 0; r < 4; ++r)
                srow[wave * QB_ROWS + mi * 16 + (lane >> 4) * 4 + r] = sm[mi][r];
    }
    __syncthreads();
    // normalize + write P (row pitch 264, linear)
#pragma unroll
    for (int mi = 0; mi < 2; ++mi)
#pragma unroll
        for (int r = 0; r < 4; ++r) {
            int row = mi * 16 + (lane >> 4) * 4 + r;
            float inv = 1.0f / (srow[row] + srow[QB_ROWS + row] +
                                srow[2 * QB_ROWS + row] + srow[3 * QB_ROWS + row]);
#pragma unroll
            for (int ni = 0; ni < 4; ++ni) {
                int col = wave * 64 + ni * 16 + (lane & 15);
                Pl[row * PPITCH + col] = (bh16)(acc[mi][ni][r] * inv);
            }
        }
    __syncthreads();

    // ---- phase 2a: wave-K-split MFMA (wave w covers k = w*64 .. w*64+63) ----
    f32x4 acc2[2][4];
#pragma unroll
    for (int i = 0; i < 2; ++i)
#pragma unroll
        for (int j = 0; j < 4; ++j) acc2[i][j] = (f32x4){0.f, 0.f, 0.f, 0.f};
#pragma unroll
    for (int kk = 0; kk < 2; ++kk) {
        int k0 = wave * 64 + kk * 32;
        bf16x8 af[2], bfr[4];
#pragma unroll
        for (int mi = 0; mi < 2; ++mi) {
            int row = mi * 16 + (lane & 15);
            af[mi] = *(const bf16x8*)(Pl + row * PPITCH + k0 + kslot * 8);
        }
#pragma unroll
        for (int ni = 0; ni < 4; ++ni) {
            int brow = ni * 16 + (lane & 15);
            bfr[ni] = *(const bf16x8*)(wbh + brow * 256 + k0 + kslot * 8);
        }
#pragma unroll
        for (int mi = 0; mi < 2; ++mi)
#pragma unroll
            for (int ni = 0; ni < 4; ++ni)
                acc2[mi][ni] = __builtin_amdgcn_mfma_f32_16x16x32_bf16(
                    af[mi], bfr[ni], acc2[mi][ni], 0, 0, 0);
    }
    __syncthreads();   // all Pl reads complete before red overlays smem

    // ---- phase 2b: deterministic 4-wave f32 reduce (pitch 68, 2-way) ----
    for (int w = 0; w < 4; ++w) {
        if (wave == w) {
#pragma unroll
            for (int mi = 0; mi < 2; ++mi)
#pragma unroll
                for (int ni = 0; ni < 4; ++ni)
#pragma unroll
                    for (int r = 0; r < 4; ++r) {
                        int row = mi * 16 + (lane >> 4) * 4 + r;
                        int col = ni * 16 + (lane & 15);
                        if (w == 0) red[row * RPITCH + col] = acc2[mi][ni][r];
                        else        red[row * RPITCH + col] += acc2[mi][ni][r];
                    }
        }
        __syncthreads();
    }

    // ---- epilogue: + conv (bf16, QKV k-slot), round, vectorized write ----
    {
        const int row = tid >> 3;              // 0..31
        const int col0 = (tid & 7) * 8;        // 0,8,...,56
        const ll nrow = (ll)(q0 + row);
        const bh16* cv = qkv + (ll)b * SMPq + nrow * 1536 + 512 + h * 64 + col0;
        bh16* op = aout + (ll)b * (NVEC * 512) + nrow * 512 + h * 64 + col0;
        bf16x8 c0 = *(const bf16x8*)cv;
        bf16x8 o0;
#pragma unroll
        for (int j = 0; j < 8; ++j)
            o0[j] = (bh16)(red[row * RPITCH + col0 + j] + (float)c0[j]);
        *(bf16x8*)op = o0;
    }
}

// ===========================================================================
// Small kernels
// ===========================================================================
__global__ void embed_k(const float* __restrict__ x, const float* __restrict__ w,
                        const float* __restrict__ b, float* __restrict__ h)
{
    ll idx = (ll)blockIdx.x * 256 + threadIdx.x;
    int d = (int)(idx & 511);
    ll bn = idx >> 9;
    h[idx] = x[bn * 2] * w[d] + x[bn * 2 + 1] * w[512 + d] + b[d];
}

__global__ void __launch_bounds__(256)
ln_k(const float* __restrict__ X, const float* __restrict__ g,
     const float* __restrict__ bta, bh16* __restrict__ Y)
{
    const ll row = blockIdx.x;
    const float* x = X + row * 512;
    bh16* y = Y + row * 512;
    const int tid = threadIdx.x;
    float v0 = x[tid], v1 = x[tid + 256];
    float s = v0 + v1;
    float q = v0 * v0 + v1 * v1;
    __shared__ float sred[8];
    for (int o = 32; o; o >>= 1) { s += __shfl_down(s, o); q += __shfl_down(q, o); }
    const int lane = tid & 63, w = tid >> 6;
    if (lane == 0) { sred[w] = s; sred[4 + w] = q; }
    __syncthreads();
    float ssum = sred[0] + sred[1] + sred[2] + sred[3];
    float qsum = sred[4] + sred[5] + sred[6] + sred[7];
    float mu = ssum * (1.0f / 512.0f);
    float var = qsum * (1.0f / 512.0f) - mu * mu;
    float r = rsqrtf(var + 1e-5f);
    y[tid] = (bh16)((v0 - mu) * r * g[tid] + bta[tid]);
    y[tid + 256] = (bh16)((v1 - mu) * r * g[tid + 256] + bta[tid + 256]);
}

__global__ void __launch_bounds__(256)
cvtT_k(const float* __restrict__ in, bh16* __restrict__ outp, int C, int R)
{
    __shared__ float t[64][65];
    const int nCt = C >> 6;
    const int c0 = (blockIdx.x % nCt) * 64;
    const int r0 = (blockIdx.x / nCt) * 64;
    const int tid = threadIdx.x;
#pragma unroll
    for (int j = 0; j < 16; ++j) {
        int idx = j * 256 + tid;
        int lr = idx >> 6, lc = idx & 63;
        t[lc][lr] = in[(ll)(r0 + lr) * C + c0 + lc];
    }
    __syncthreads();
#pragma unroll
    for (int v = 0; v < 2; ++v) {
        int flat = v * 256 + tid;
        int lc = flat >> 3, r8 = (flat & 7) * 8;
        bf16x8 o;
#pragma unroll
        for (int j = 0; j < 8; ++j) o[j] = (bh16)t[lc][r8 + j];
        *(bf16x8*)(outp + (ll)(c0 + lc) * R + r0 + r8) = o;
    }
}

__global__ void landmarks_k(const bh16* __restrict__ qkv,
                            bh16* __restrict__ qlb, bh16* __restrict__ klb)
{
    int idx = blockIdx.x * 256 + threadIdx.x;
    int d = idx & 63;
    int m = (idx >> 6) & 255;
    int h = (idx >> 14) & 7;
    int b = idx >> 17;
    const bh16* base = qkv + (ll)b * (NVEC * 1536) + (ll)(m * LSEG) * 1536 + h * 64 + d;
    float sq = 0.f, sk = 0.f;
#pragma unroll
    for (int l = 0; l < LSEG; ++l) {
        sq += (float)base[(ll)l * 1536];
        sk += (float)base[(ll)l * 1536 + 512];
    }
    ll o = (ll)(b * 8 + h) * 16384 + m * 64 + d;
    qlb[o] = (bh16)(sq * (0.0625f * 0.125f));
    klb[o] = (bh16)(sk * 0.0625f);
}

__global__ void wbt_k(const bh16* __restrict__ wb, bh16* __restrict__ wbt)
{
    int idx = blockIdx.x * 256 + threadIdx.x;
    int d = idx & 63, kg = (idx >> 6) & 31, bhh = idx >> 11;
    const bh16* p = wb + (ll)bhh * 16384 + kg * 8 * 64 + d;
    bf16x8 o;
#pragma unroll
    for (int j = 0; j < 8; ++j) o[j] = p[j * 64];
    *(bf16x8*)(wbt + (ll)bhh * 16384 + d * 256 + kg * 8) = o;
}

// reduce split-K partials for a 2-sample chunk:
// part [2][8h][8s][256][64] f32 -> A3Vb bf16 at [bh0+smp*8+h][256][64]
__global__ void a3vred_k(const float* __restrict__ part, bh16* __restrict__ outp)
{
    int idx = blockIdx.x * 256 + threadIdx.x;   // 262144
    int smp = idx >> 17;
    int rest = idx & 131071;
    int h = rest >> 14, o = rest & 16383;
    const float* p = part + (ll)smp * 1048576 + (ll)h * 131072 + o;
    float s = 0.f;
#pragma unroll
    for (int j = 0; j < 8; ++j) s += p[j * 16384];
    outp[(ll)(smp * 8 + h) * 16384 + o] = (bh16)s;
}

__global__ void __launch_bounds__(256)
conv_k(bh16* __restrict__ qkv, const float* __restrict__ cw)
{
    int idx = blockIdx.x * 256 + threadIdx.x;
    int c8 = idx & 63;
    int ng = (idx >> 6) & 1023;
    int b  = idx >> 16;
    const int n0 = ng * 4;
    const int h = c8 >> 3;
    const bh16* v = qkv + (ll)b * (NVEC * 1536) + 1024 + c8 * 8;

    float wreg[KER];
#pragma unroll
    for (int k = 0; k < KER; ++k) wreg[k] = cw[h * KER + k];

    float acc[4][8];
#pragma unroll
    for (int t = 0; t < 4; ++t)
#pragma unroll
        for (int e = 0; e < 8; ++e) acc[t][e] = 0.f;

#pragma unroll
    for (int m = 0; m < 36; ++m) {
        int nn = n0 + m - (KER / 2);
        bf16x8 vv = {};
        if ((unsigned)nn < (unsigned)NVEC)
            vv = *(const bf16x8*)(v + (ll)nn * 1536);
#pragma unroll
        for (int t = 0; t < 4; ++t) {
            constexpr int KMAX = KER - 1;
            int k = m - t;
            if (k >= 0 && k <= KMAX) {
                float wk = wreg[k];
#pragma unroll
                for (int e = 0; e < 8; ++e)
                    acc[t][e] = fmaf((float)vv[e], wk, acc[t][e]);
            }
        }
    }

    bh16* o = qkv + (ll)b * (NVEC * 1536) + (ll)n0 * 1536 + 512 + c8 * 8;
#pragma unroll
    for (int t = 0; t < 4; ++t) {
        bf16x8 ov;
#pragma unroll
        for (int e = 0; e < 8; ++e) ov[e] = (bh16)acc[t][e];
        *(bf16x8*)(o + (ll)t * 1536) = ov;
    }
}

__device__ __forceinline__ float blkmax(float m, float* red, int tid)
{
#pragma unroll
    for (int o = 32; o; o >>= 1) m = fmaxf(m, __shfl_down(m, o));
    if ((tid & 63) == 0) red[tid >> 6] = m;
    __syncthreads();
    m = fmaxf(fmaxf(red[0], red[1]), fmaxf(red[2], red[3]));
    __syncthreads();
    return m;
}
__device__ __forceinline__ float blksum(float s, float* red, int tid)
{
#pragma unroll
    for (int o = 32; o; o >>= 1) s += __shfl_down(s, o);
    if ((tid & 63) == 0) red[tid >> 6] = s;
    __syncthreads();
    s = red[0] + red[1] + red[2] + red[3];
    __syncthreads();
    return s;
}

// in-place bf16 row softmax, L == 4096; one block (256 thr) per row
__global__ void __launch_bounds__(256)
softmax_bf_k(bh16* __restrict__ X, int L)
{
    const ll row = blockIdx.x;
    bh16* x = X + row * (ll)L;
    const int tid = threadIdx.x;
    __shared__ float red[4];
    float v[16];
    bf16x8 a = *(const bf16x8*)(x + tid * 8);
    bf16x8 b = *(const bf16x8*)(x + 2048 + tid * 8);
#pragma unroll
    for (int j = 0; j < 8; ++j) { v[j] = (float)a[j]; v[8 + j] = (float)b[j]; }
    float m = -1e30f;
#pragma unroll
    for (int j = 0; j < 16; ++j) m = fmaxf(m, v[j]);
    m = blkmax(m, red, tid);
    float s = 0.f;
#pragma unroll
    for (int j = 0; j < 16; ++j) { v[j] = __expf(v[j] - m); s += v[j]; }
    s = blksum(s, red, tid);
    float inv = 1.0f / s;
    bf16x8 oa, ob;
#pragma unroll
    for (int j = 0; j < 8; ++j) { oa[j] = (bh16)(v[j] * inv); ob[j] = (bh16)(v[8 + j] * inv); }
    *(bf16x8*)(x + tid * 8) = oa;
    *(bf16x8*)(x + 2048 + tid * 8) = ob;
}

__global__ void __launch_bounds__(256)
pinv_init_k(const bh16* __restrict__ X, bh16* __restrict__ Z)
{
    const ll bh = blockIdx.x;
    const bh16* x = X + bh * 65536;
    bh16* z = Z + bh * 65536;
    const int tid = threadIdx.x;
    float rs = 0.f, cs = 0.f;
    for (int j = 0; j < 256; ++j) {
        rs += fabsf((float)x[tid * 256 + j]);
        cs += fabsf((float)x[j * 256 + tid]);
    }
    __shared__ float rbuf[256], cbuf[256];
    rbuf[tid] = rs; cbuf[tid] = cs;
    __syncthreads();
    for (int o = 128; o; o >>= 1) {
        if (tid < o) {
            rbuf[tid] = fmaxf(rbuf[tid], rbuf[tid + o]);
            cbuf[tid] = fmaxf(cbuf[tid], cbuf[tid + o]);
        }
        __syncthreads();
    }
    float inv = 1.0f / (rbuf[0] * cbuf[0]);
    for (int e = tid; e < 65536; e += 256) {
        int i = e >> 8, j = e & 255;
        z[e] = (bh16)((float)x[j * 256 + i] * inv);
    }
}

__global__ void final_init_k(const float* __restrict__ fb, float* __restrict__ out)
{
    int i = threadIdx.x;
    if (i < BB_ * NCLASS) out[i] = fb[i % NCLASS];
}

__global__ void __launch_bounds__(256)
final_gemv_k(const float* __restrict__ hbuf, const float* __restrict__ w,
             float* __restrict__ out)
{
    const int half = blockIdx.y;
    const int chunk = blockIdx.x;
    const int tid = threadIdx.x;
    const int k0 = chunk * 8192;
    float pc[4][NCLASS] = {};
    for (int e = 0; e < 32; ++e) {
        int k = k0 + e * 256 + tid;
        const float* wr = w + (ll)k * NCLASS;
        float wv[NCLASS];
#pragma unroll
        for (int c = 0; c < NCLASS; ++c) wv[c] = wr[c];
#pragma unroll
        for (int b = 0; b < 4; ++b) {
            float hv = hbuf[(ll)(half * 4 + b) * (NVEC * DIM) + k];
#pragma unroll
            for (int c = 0; c < NCLASS; ++c) pc[b][c] = fmaf(hv, wv[c], pc[b][c]);
        }
    }
    __shared__ float red[4][4][NCLASS];
    const int lane = tid & 63, wv_ = tid >> 6;
#pragma unroll
    for (int b = 0; b < 4; ++b)
#pragma unroll
        for (int c = 0; c < NCLASS; ++c) {
            float s = pc[b][c];
#pragma unroll
            for (int o = 32; o; o >>= 1) s += __shfl_down(s, o);
            if (lane == 0) red[wv_][b][c] = s;
        }
    __syncthreads();
    if (tid < 4 * NCLASS) {
        int b = tid / NCLASS, c = tid % NCLASS;
        float s = red[0][b][c] + red[1][b][c] + red[2][b][c] + red[3][b][c];
        atomicAdd(out + (half * 4 + b) * NCLASS + c, s);
    }
}

// ===========================================================================
extern "C" void kernel_launch(void* const* d_in, const int* in_sizes, int n_in,
                              void* d_out, int out_size, void* d_ws, size_t ws_size,
                              hipStream_t stream)
{
    const float* x      = (const float*)d_in[0];
    const float* lin_w  = (const float*)d_in[1];
    const float* lin_b  = (const float*)d_in[2];
    const float* ln1_g  = (const float*)d_in[3];
    const float* ln1_b  = (const float*)d_in[4];
    const float* qkv_w  = (const float*)d_in[5];
    const float* out_w  = (const float*)d_in[6];
    const float* out_b  = (const float*)d_in[7];
    const float* conv_w = (const float*)d_in[8];
    const float* ln2_g  = (const float*)d_in[9];
    const float* ln2_b  = (const float*)d_in[10];
    const float* ff1_w  = (const float*)d_in[11];
    const float* ff1_b  = (const float*)d_in[12];
    const float* ff2_w  = (const float*)d_in[13];
    const float* ff2_b  = (const float*)d_in[14];
    const float* final_w = (const float*)d_in[15];
    const float* final_b = (const float*)d_in[16];
    float* out = (float*)d_out;
    float* ws  = (float*)d_ws;

    // ---- workspace layout (f32 units), total 56,623,104 f32 = 226.5 MB ----
    float* H    = ws;                                  // [8][4096][512] f32
    bh16*  QKV  = (bh16*)(ws + 16777216);              // [8][4096][1536] bf16
    float* P    = ws + 41943040;                       // pool, 10,485,760 f32
    bh16*  qlbf = (bh16*)(ws + 52428800);              // [64bh][256][64] bf16
    bh16*  klbf = (bh16*)(ws + 52953088);
    bh16*  A3Vb = (bh16*)(ws + 53477376);              // [64bh][256][64] bf16
    bh16*  WBb  = (bh16*)(ws + 54001664);
    bh16*  WBT  = (bh16*)(ws + 54525952);              // [64bh][64][256] bf16
    bh16*  WQT  = (bh16*)(ws + 55050240);              // [1536][512] bf16
    bh16*  WOT  = (bh16*)(ws + 55443456);              // [512][512] bf16
    bh16*  F1WT = (bh16*)(ws + 55574528);              // [2048][512] bf16
    bh16*  F2WT = (bh16*)(ws + 56098816);              // [512][2048] bf16
    if (ws_size < 56623104ULL * 4) return;

    // pool aliases (time-sliced)
    bh16*  XLNall = (bh16*)P;                          // [32768][512] bf16
    bh16*  ATT3c  = (bh16*)P;                          // [16bh][256][4096] bf16
    float* A3Vp   = P + 8388608;                       // [2][8h][8s][256][64] f32
    bh16*  Xbf = (bh16*)P;                             // pinv: 5 x [64][256][256] bf16
    bh16*  Z0  = (bh16*)(P + 2097152);
    bh16*  Z1  = (bh16*)(P + 4194304);
    bh16*  T1  = (bh16*)(P + 6291456);
    bh16*  T2  = (bh16*)(P + 8388608);
    bh16*  AOUTa  = (bh16*)P;                          // [8][4096][512] bf16
    bh16*  XLNc   = (bh16*)P;                          // FFN: [8192][512] bf16
    bh16*  HIDc   = (bh16*)(P + 2097152);              // [2][4096][2048] bf16

    const ll SMP = (ll)NVEC * 1536;

    hipLaunchKernelGGL(embed_k, dim3(65536), dim3(256), 0, stream, x, lin_w, lin_b, H);

    for (int i = 0; i < DEPTH; ++i) {
        const float* wq  = qkv_w + (ll)i * 512 * 1536;
        const float* wo  = out_w + (ll)i * 512 * 512;
        const float* bo  = out_b + (ll)i * 512;
        const float* cw  = conv_w + (ll)i * HEADS * KER;
        const float* g1  = ln1_g + (ll)i * 512;
        const float* b1  = ln1_b + (ll)i * 512;
        const float* g2  = ln2_g + (ll)i * 512;
        const float* b2  = ln2_b + (ll)i * 512;
        const float* f1w = ff1_w + (ll)i * 512 * 2048;
        const float* f1b = ff1_b + (ll)i * 2048;
        const float* f2w = ff2_w + (ll)i * 2048 * 512;
        const float* f2b = ff2_b + (ll)i * 512;

        hipLaunchKernelGGL(cvtT_k, dim3(192), dim3(256), 0, stream, wq, WQT, 1536, 512);
        hipLaunchKernelGGL(cvtT_k, dim3(64), dim3(256), 0, stream, wo, WOT, 512, 512);
        hipLaunchKernelGGL(cvtT_k, dim3(256), dim3(256), 0, stream, f1w, F1WT, 2048, 512);
        hipLaunchKernelGGL(cvtT_k, dim3(256), dim3(256), 0, stream, f2w, F2WT, 512, 2048);

        // LN1 + qkv (M=32768)
        hipLaunchKernelGGL(ln_k, dim3(32768), dim3(256), 0, stream, H, g1, b1, XLNall);
        mg<2,2,0,0,0,1,0,0>(stream, 32768, 1536, 512, XLNall, 512, WQT, 512,
            QKV, 1536, nullptr, nullptr, 1, 1, 0,0, 0,0, 0,0, 1.f, 0.f);

        hipLaunchKernelGGL(landmarks_k, dim3(4096), dim3(256), 0, stream, QKV, qlbf, klbf);

        // ---- attn3 / softmax / a3v in 2-sample chunks (bf16 scores) ----
        for (int c = 0; c < 4; ++c) {
            const bh16* qkvc = QKV + (ll)c * 2 * SMP;
            mg<2,2,0,0,0,1,0,0>(stream, 256, 4096, 64,
                qlbf + (ll)c * 262144, 64, qkvc + 512, 1536,
                ATT3c, 4096, nullptr, nullptr, 16, 8,
                131072, 16384, SMP, 64, 8388608LL, 1048576, 1.f, 0.f);
            hipLaunchKernelGGL(softmax_bf_k, dim3(4096), dim3(256), 0, stream, ATT3c, 4096);
            for (int s = 0; s < 2; ++s) {
                mg<4,1,1,0,0,0,0,0>(stream, 256, 64, 512,
                    ATT3c + (ll)s * 8 * 1048576, 4096, qkvc + (ll)s * SMP + 1024, 1536,
                    A3Vp + (ll)s * 1048576, 64, nullptr, nullptr, 64, 8,
                    1048576, 512, 64, 512LL * 1536, 131072, 16384, 1.f, 0.f);
            }
            hipLaunchKernelGGL(a3vred_k, dim3(1024), dim3(256), 0, stream,
                               A3Vp, A3Vb + (ll)c * 2 * 131072);
        }

        // conv -> QKV k-slot (k fully consumed above)
        hipLaunchKernelGGL(conv_k, dim3(2048), dim3(256), 0, stream, QKV, cw);

        // ---- pinv (bf16 MFMA, batched 64); X via fused-softmax GEMM ----
        mg<1,4,0,0,0,1,0,1>(stream, 256, 256, 64, qlbf, 64, klbf, 64,
            Xbf, 256, nullptr, nullptr, 64, 64, 0, 16384, 0, 16384, 0, 65536, 1.f, 0.f);
        hipLaunchKernelGGL(pinv_init_k, dim3(64), dim3(256), 0, stream, Xbf, Z0);
        bh16* zc = Z0; bh16* zn = Z1;
        for (int it = 0; it < ITERS; ++it) {
            mg<2,2,1,0,0,1,1,0>(stream, 256, 256, 256, Xbf, 256, zc, 256,
                T1, 256, T2, nullptr, 64, 64, 0, 65536, 0, 65536, 0, 65536, 1.f, 7.f);
            mg<2,2,1,0,0,1,0,0>(stream, 256, 256, 256, T1, 256, T2, 256,
                zn, 256, nullptr, nullptr, 64, 64, 0, 65536, 0, 65536, 0, 65536, -1.f, 15.f);
            mg<2,2,1,0,0,1,0,0>(stream, 256, 256, 256, T1, 256, zn, 256,
                T2, 256, nullptr, nullptr, 64, 64, 0, 65536, 0, 65536, 0, 65536, -1.f, 13.f);
            mg<2,2,1,0,0,1,0,0>(stream, 256, 256, 256, zc, 256, T2, 256,
                zn, 256, nullptr, nullptr, 64, 64, 0, 65536, 0, 65536, 0, 65536, 0.25f, 0.f);
            bh16* t = zc; zc = zn; zn = t;
        }
        mg<4,1,1,0,0,1,0,0>(stream, 256, 64, 256, zc, 256, A3Vb, 64,
            WBb, 64, nullptr, nullptr, 64, 64, 0, 65536, 0, 16384, 0, 16384, 1.f, 0.f);
        hipLaunchKernelGGL(wbt_k, dim3(512), dim3(256), 0, stream, WBb, WBT);

        // ---- fused attn1 + P@wb + conv -> AOUTa; then one out-proj ----
        hipLaunchKernelGGL(fattn_k, dim3(128, 64), dim3(256), 0, stream,
                           QKV, klbf, WBT, AOUTa);
        mg<2,2,0,0,1,0,0,0>(stream, 32768, 512, 512, AOUTa, 512, WOT, 512,
            H, 512, nullptr, bo, 1, 1, 0,0, 0,0, 0,0, 1.f, 0.f);

        // ---- FFN in 2-sample chunks ----
        for (int c = 0; c < 4; ++c) {
            float* Hc = H + (ll)c * 2 * 2097152;
            hipLaunchKernelGGL(ln_k, dim3(8192), dim3(256), 0, stream, Hc, g2, b2, XLNc);
            mg<2,2,0,1,0,1,0,0>(stream, 8192, 2048, 512, XLNc, 512, F1WT, 512,
                HIDc, 2048, nullptr, f1b, 1, 1, 0,0, 0,0, 0,0, 1.f, 0.f);
            mg<2,2,0,0,1,0,0,0>(stream, 8192, 512, 2048, HIDc, 2048, F2WT, 2048,
                Hc, 512, nullptr, f2b, 1, 1, 0,0, 0,0, 0,0, 1.f, 0.f);
        }
    }

    hipLaunchKernelGGL(final_init_k, dim3(1), dim3(128), 0, stream, final_b, out);
    hipLaunchKernelGGL(final_gemv_k, dim3(256, 2), dim3(256), 0, stream, H, final_w, out);
}

// Round 21
// 3063.917 us; speedup vs baseline: 1.0556x; 1.0268x over previous
//
#include <hip/hip_runtime.h>
#include <hip/hip_bf16.h>

// Problem constants
#define BB_ 8
#define NVEC 4096
#define DIM 512
#define HEADS 8
#define DH 64
#define MM_ 256
#define ITERS 6
#define DEPTH 2
#define NCLASS 10
#define KER 33
#define INNER 512
#define LSEG 16  // NVEC / MM_

typedef long long ll;
typedef __bf16 bh16;
typedef __attribute__((ext_vector_type(8))) __bf16 bf16x8;
typedef __attribute__((ext_vector_type(4))) float f32x4;

// ===========================================================================
// MFMA bf16 GEMM. TRB=0 (TN): C = A[M,K] @ B_t[N,K]^T. TRB=1 (NN).
// Tile BM=WR*64 x BN=WC*64, 256 threads = 4 waves (WR*WC==4).
// KH = K-halves (32 each) staged per barrier round; KSTEP = KH*32. Each
// half goes to its OWN LDS plane with the proven linear global_load_lds
// pattern (dest = wave base + lane*16, m104-conforming; per-plane bank
// behavior identical to KH=1). MFMA chain runs plane 0 then plane 1 ->
// per-accumulator K-order unchanged -> BIT-IDENTICAL results; barriers
// per K-step halve for KH=2.
// XCD-bijective block swizzle (m204). SMAX: fused row-softmax (WR==1,
// gridDim.x==1). DUAL: C=acc, C2=diagv*I-acc. Batch: z -> bo=z/BI, bi=z%BI.
// ===========================================================================
template<int WR, int WC, int KH, bool TRB, bool GELU_ACT, bool RESID,
         bool BF16OUT, bool DUAL, bool SMAX>
__global__ void __launch_bounds__(256)
mgemm_k(const bh16* __restrict__ A, const bh16* __restrict__ B,
        const float* __restrict__ bias, void* __restrict__ Cv, void* __restrict__ C2v,
        int K, int lda, int ldb, int ldc,
        int BI, ll sAo, ll sAi, ll sBo, ll sBi, ll sCo, ll sCi,
        float alpha, float diagv)
{
    constexpr int BM = WR * 64, BN = WC * 64;
    constexpr int KSTEP = KH * 32;
    const int bz = blockIdx.z;
    const int bo = bz / BI, bi = bz % BI;
    const bh16* Ab = A + bo * sAo + (ll)bi * sAi;
    const bh16* Bb = B + bo * sBo + (ll)bi * sBi;
    const ll coff = bo * sCo + (ll)bi * sCi;

    const int gx = gridDim.x;
    const int nwg = gx * gridDim.y;
    int flat = blockIdx.y * gx + blockIdx.x;
    {
        int xcd = flat & 7, base = flat >> 3;
        int q = nwg >> 3, rr = nwg & 7;
        flat = (xcd < rr ? xcd * (q + 1) : rr * (q + 1) + (xcd - rr) * q) + base;
    }
    const int m0 = (flat / gx) * BM;
    const int n0 = (flat % gx) * BN;

    const int tid = threadIdx.x;
    const int lane = tid & 63;
    const int wave = tid >> 6;
    const int wr = wave / WC, wc = wave % WC;

    __shared__ bh16 Al[KH * BM * 32];
    __shared__ bh16 Bl[KH * BN * 32];
    __shared__ float srow[SMAX ? 4 * 64 : 4];

    f32x4 acc[4][4];
#pragma unroll
    for (int i = 0; i < 4; ++i)
#pragma unroll
        for (int j = 0; j < 4; ++j) acc[i][j] = (f32x4){0.f, 0.f, 0.f, 0.f};

    const int srowi = tid >> 2;  // 0..63
    const int ssl   = tid & 3;   // 16B slot (linear LDS dest)

    const int rsel  = ((lane & 15) >> 1) & 3;
    const int kslot = lane >> 4;

    for (int k0 = 0; k0 < K; k0 += KSTEP) {
        __syncthreads();
#pragma unroll
        for (int hh = 0; hh < KH; ++hh) {
            bh16* Alp = Al + hh * BM * 32;
            bh16* Blp = Bl + hh * BN * 32;
            const int kk0 = k0 + hh * 32;
#pragma unroll
            for (int i = 0; i < BM / 64; ++i) {
                int row = i * 64 + srowi;
                int gsl = ssl ^ ((row >> 1) & 3);
                __builtin_amdgcn_global_load_lds(
                    (const __attribute__((address_space(1))) unsigned int*)
                        (Ab + (ll)(m0 + row) * lda + kk0 + gsl * 8),
                    (__attribute__((address_space(3))) unsigned int*)
                        (Alp + row * 32 + ssl * 8),
                    16, 0, 0);
            }
            if (!TRB) {
#pragma unroll
                for (int i = 0; i < BN / 64; ++i) {
                    int row = i * 64 + srowi;
                    int gsl = ssl ^ ((row >> 1) & 3);
                    __builtin_amdgcn_global_load_lds(
                        (const __attribute__((address_space(1))) unsigned int*)
                            (Bb + (ll)(n0 + row) * ldb + kk0 + gsl * 8),
                        (__attribute__((address_space(3))) unsigned int*)
                            (Blp + row * 32 + ssl * 8),
                        16, 0, 0);
                }
            } else {
                const int bk = tid >> 3;
                const int nb0 = (tid & 7) * (BN / 8);
#pragma unroll
                for (int v8 = 0; v8 < BN / 64; ++v8) {
                    int nb = nb0 + v8 * 8;
                    bf16x8 v = *(const bf16x8*)(Bb + (ll)(kk0 + bk) * ldb + n0 + nb);
#pragma unroll
                    for (int j = 0; j < 8; ++j) {
                        int n = nb + j;
                        int sl = (bk >> 3) ^ ((n >> 1) & 3);
                        Blp[n * 32 + sl * 8 + (bk & 7)] = v[j];
                    }
                }
            }
        }
        __syncthreads();

#pragma unroll
        for (int hh = 0; hh < KH; ++hh) {
            const bh16* Alp = Al + hh * BM * 32;
            const bh16* Blp = Bl + hh * BN * 32;
            bf16x8 af[4], bfr[4];
#pragma unroll
            for (int mi = 0; mi < 4; ++mi) {
                int row = wr * 64 + mi * 16 + (lane & 15);
                af[mi] = *(const bf16x8*)(Alp + row * 32 + (kslot ^ rsel) * 8);
            }
#pragma unroll
            for (int ni = 0; ni < 4; ++ni) {
                int row = wc * 64 + ni * 16 + (lane & 15);
                bfr[ni] = *(const bf16x8*)(Blp + row * 32 + (kslot ^ rsel) * 8);
            }
#pragma unroll
            for (int mi = 0; mi < 4; ++mi)
#pragma unroll
                for (int ni = 0; ni < 4; ++ni)
                    acc[mi][ni] = __builtin_amdgcn_mfma_f32_16x16x32_bf16(
                        af[mi], bfr[ni], acc[mi][ni], 0, 0, 0);
        }
    }

    if (SMAX) {
        bh16* Cb = (bh16*)Cv;
#pragma unroll
        for (int mi = 0; mi < 4; ++mi)
#pragma unroll
            for (int ni = 0; ni < 4; ++ni)
#pragma unroll
                for (int r = 0; r < 4; ++r) acc[mi][ni][r] *= alpha;
        float mx[4][4];
#pragma unroll
        for (int mi = 0; mi < 4; ++mi)
#pragma unroll
            for (int r = 0; r < 4; ++r) {
                float m_ = acc[mi][0][r];
#pragma unroll
                for (int ni = 1; ni < 4; ++ni) m_ = fmaxf(m_, acc[mi][ni][r]);
#pragma unroll
                for (int msk = 1; msk < 16; msk <<= 1)
                    m_ = fmaxf(m_, __shfl_xor(m_, msk));
                mx[mi][r] = m_;
            }
        if ((lane & 15) == 0) {
#pragma unroll
            for (int mi = 0; mi < 4; ++mi)
#pragma unroll
                for (int r = 0; r < 4; ++r)
                    srow[wc * 64 + mi * 16 + (lane >> 4) * 4 + r] = mx[mi][r];
        }
        __syncthreads();
        float M_[4][4];
#pragma unroll
        for (int mi = 0; mi < 4; ++mi)
#pragma unroll
            for (int r = 0; r < 4; ++r) {
                int row = mi * 16 + (lane >> 4) * 4 + r;
                M_[mi][r] = fmaxf(fmaxf(srow[row], srow[64 + row]),
                                  fmaxf(srow[128 + row], srow[192 + row]));
            }
        __syncthreads();
        float sm[4][4];
#pragma unroll
        for (int mi = 0; mi < 4; ++mi)
#pragma unroll
            for (int r = 0; r < 4; ++r) {
                float s_ = 0.f;
#pragma unroll
                for (int ni = 0; ni < 4; ++ni) {
                    float e = __expf(acc[mi][ni][r] - M_[mi][r]);
                    acc[mi][ni][r] = e;
                    s_ += e;
                }
#pragma unroll
                for (int msk = 1; msk < 16; msk <<= 1)
                    s_ += __shfl_xor(s_, msk);
                sm[mi][r] = s_;
            }
        if ((lane & 15) == 0) {
#pragma unroll
            for (int mi = 0; mi < 4; ++mi)
#pragma unroll
                for (int r = 0; r < 4; ++r)
                    srow[wc * 64 + mi * 16 + (lane >> 4) * 4 + r] = sm[mi][r];
        }
        __syncthreads();
#pragma unroll
        for (int mi = 0; mi < 4; ++mi)
#pragma unroll
            for (int r = 0; r < 4; ++r) {
                int row = mi * 16 + (lane >> 4) * 4 + r;
                float inv = 1.0f / (srow[row] + srow[64 + row] +
                                    srow[128 + row] + srow[192 + row]);
                int rowg = m0 + row;
#pragma unroll
                for (int ni = 0; ni < 4; ++ni) {
                    int colg = n0 + wc * 64 + ni * 16 + (lane & 15);
                    Cb[coff + (ll)rowg * ldc + colg] = (bh16)(acc[mi][ni][r] * inv);
                }
            }
        return;
    }

#pragma unroll
    for (int mi = 0; mi < 4; ++mi) {
#pragma unroll
        for (int ni = 0; ni < 4; ++ni) {
            const int colg = n0 + wc * 64 + ni * 16 + (lane & 15);
            const float bia = (!DUAL && bias) ? bias[colg] : 0.f;
#pragma unroll
            for (int r = 0; r < 4; ++r) {
                const int rowg = m0 + wr * 64 + mi * 16 + (lane >> 4) * 4 + r;
                const float a = acc[mi][ni][r];
                const ll off = coff + (ll)rowg * ldc + colg;
                if (DUAL) {
                    ((bh16*)Cv)[off] = (bh16)a;
                    float w = ((rowg == colg) ? diagv : 0.f) - a;
                    ((bh16*)C2v)[off] = (bh16)w;
                } else {
                    float v = alpha * a + bia;
                    if (diagv != 0.f && rowg == colg) v += diagv;
                    if (GELU_ACT) {
                        float t = tanhf(0.7978845608f * (v + 0.044715f * v * v * v));
                        v = 0.5f * v * (1.0f + t);
                    }
                    if (BF16OUT) {
                        ((bh16*)Cv)[off] = (bh16)v;
                    } else {
                        float* p = (float*)Cv + off;
                        float o = v;
                        if (RESID) o += *p;
                        *p = o;
                    }
                }
            }
        }
    }
}

template<int WR, int WC, int KH, bool TRB, bool G, bool R, bool BO, bool D, bool SX>
static inline void mg(hipStream_t s, int M, int N, int K,
                      const bh16* A, int lda, const bh16* B, int ldb,
                      void* C, int ldc, void* C2, const float* bias,
                      int batch, int BI,
                      ll sAo, ll sAi, ll sBo, ll sBi, ll sCo, ll sCi,
                      float alpha, float diagv)
{
    dim3 grid(N / (WC * 64), M / (WR * 64), batch);
    hipLaunchKernelGGL((mgemm_k<WR, WC, KH, TRB, G, R, BO, D, SX>), grid, dim3(256), 0, s,
                       A, B, bias, C, C2, K, lda, ldb, ldc, BI,
                       sAo, sAi, sBo, sBi, sCo, sCi, alpha, diagv);
}

// ===========================================================================
// Fused attn1. Block = (32 q-rows, one (b,h)) -- measured-optimal q-block
// (TLP sweep: QB64=114us, QB32=99us, QB16=146us). Per-row math BIT-IDENTICAL
// across QB variants (same MFMA chains, softmax tree, rounding sites).
// Phase 1: S=q@kl^T (K=64), cross-wave softmax (alpha 0.125), P -> LDS
//   (pitch 264, linear). Phase 2: wave-K-split + f32 LDS reduce (pitch 68)
//   aliased over Pl (barrier-separated). Vectorized bf16x8 epilogue + conv.
// ===========================================================================
#define QB_ROWS 32
#define PPITCH 264
#define RPITCH 68
__global__ void __launch_bounds__(256)
fattn_k(const bh16* __restrict__ qkv, const bh16* __restrict__ klb,
        const bh16* __restrict__ wbt, bh16* __restrict__ aout)
{
    const int qb = blockIdx.x;          // 0..127
    const int bh = blockIdx.y;          // 0..63
    const int b = bh >> 3, h = bh & 7;
    const int q0 = qb * QB_ROWS;
    const int tid = threadIdx.x, lane = tid & 63, wave = tid >> 6;
    const ll SMPq = (ll)NVEC * 1536;

    __shared__ __align__(16) char smem[QB_ROWS * PPITCH * 2];  // 16,896 B
    bh16*  Pl  = (bh16*)smem;                                  // phase 1-2a
    float* red = (float*)smem;                                 // phase 2b (aliased)
    __shared__ float srow[4 * QB_ROWS];                        // 512 B

    const bh16* qbase = qkv + (ll)b * SMPq + (ll)q0 * 1536 + h * 64;
    const bh16* klbh = klb + (ll)bh * 16384;
    const bh16* wbh  = wbt + (ll)bh * 16384;

    const int kslot = lane >> 4;

    // ---- phase 1: scores (wave covers cols wave*64..wave*64+63) ----
    f32x4 acc[2][4];
#pragma unroll
    for (int i = 0; i < 2; ++i)
#pragma unroll
        for (int j = 0; j < 4; ++j) acc[i][j] = (f32x4){0.f, 0.f, 0.f, 0.f};
#pragma unroll
    for (int ks = 0; ks < 2; ++ks) {
        int k0 = ks * 32;
        bf16x8 af[2], bfr[4];
#pragma unroll
        for (int mi = 0; mi < 2; ++mi) {
            int row = mi * 16 + (lane & 15);
            af[mi] = *(const bf16x8*)(qbase + (ll)row * 1536 + k0 + kslot * 8);
        }
#pragma unroll
        for (int ni = 0; ni < 4; ++ni) {
            int brow = wave * 64 + ni * 16 + (lane & 15);
            bfr[ni] = *(const bf16x8*)(klbh + brow * 64 + k0 + kslot * 8);
        }
#pragma unroll
        for (int mi = 0; mi < 2; ++mi)
#pragma unroll
            for (int ni = 0; ni < 4; ++ni)
                acc[mi][ni] = __builtin_amdgcn_mfma_f32_16x16x32_bf16(
                    af[mi], bfr[ni], acc[mi][ni], 0, 0, 0);
    }

    // ---- softmax over 256 cols (4 wave-quadrants) ----
#pragma unroll
    for (int mi = 0; mi < 2; ++mi)
#pragma unroll
        for (int ni = 0; ni < 4; ++ni)
#pragma unroll
            for (int r = 0; r < 4; ++r) acc[mi][ni][r] *= 0.125f;
    float mx[2][4];
#pragma unroll
    for (int mi = 0; mi < 2; ++mi)
#pragma unroll
        for (int r = 0; r < 4; ++r) {
            float m_ = acc[mi][0][r];
#pragma unroll
            for (int ni = 1; ni < 4; ++ni) m_ = fmaxf(m_, acc[mi][ni][r]);
#pragma unroll
            for (int msk = 1; msk < 16; msk <<= 1)
                m_ = fmaxf(m_, __shfl_xor(m_, msk));
            mx[mi][r] = m_;
        }
    if ((lane & 15) == 0) {
#pragma unroll
        for (int mi = 0; mi < 2; ++mi)
#pragma unroll
            for (int r = 0; r < 4; ++r)
                srow[wave * QB_ROWS + mi * 16 + (lane >> 4) * 4 + r] = mx[mi][r];
    }
    __syncthreads();
    float M_[2][4];
#pragma unroll
    for (int mi = 0; mi < 2; ++mi)
#pragma unroll
        for (int r = 0; r < 4; ++r) {
            int row = mi * 16 + (lane >> 4) * 4 + r;
            M_[mi][r] = fmaxf(fmaxf(srow[row], srow[QB_ROWS + row]),
                              fmaxf(srow[2 * QB_ROWS + row], srow[3 * QB_ROWS + row]));
        }
    __syncthreads();
    float sm[2][4];
#pragma unroll
    for (int mi = 0; mi < 2; ++mi)
#pragma unroll
        for (int r = 0; r < 4; ++r) {
            float s_ = 0.f;
#pragma unroll
            for (int ni = 0; ni < 4; ++ni) {
                float e = __expf(acc[mi][ni][r] - M_[mi][r]);
                acc[mi][ni][r] = e;
                s_ += e;
            }
#pragma unroll
            for (int msk = 1; msk < 16; msk <<= 1)
                s_ += __shfl_xor(s_, msk);
            sm[mi][r] = s_;
        }
    if ((lane & 15) == 0) {
#pragma unroll
        for (int mi = 0; mi < 2; ++mi)
#pragma unroll
            for (int r = 0; r < 4; ++r)
                srow[wave * QB_ROWS + mi * 16 + (lane >> 4) * 4 + r] = sm[mi][r];
    }
    __syncthreads();
    // normalize + write P (row pitch 264, linear)
#pragma unroll
    for (int mi = 0; mi < 2; ++mi)
#pragma unroll
        for (int r = 0; r < 4; ++r) {
            int row = mi * 16 + (lane >> 4) * 4 + r;
            float inv = 1.0f / (srow[row] + srow[QB_ROWS + row] +
                                srow[2 * QB_ROWS + row] + srow[3 * QB_ROWS + row]);
#pragma unroll
            for (int ni = 0; ni < 4; ++ni) {
                int col = wave * 64 + ni * 16 + (lane & 15);
                Pl[row * PPITCH + col] = (bh16)(acc[mi][ni][r] * inv);
            }
        }
    __syncthreads();

    // ---- phase 2a: wave-K-split MFMA (wave w covers k = w*64 .. w*64+63) ----
    f32x4 acc2[2][4];
#pragma unroll
    for (int i = 0; i < 2; ++i)
#pragma unroll
        for (int j = 0; j < 4; ++j) acc2[i][j] = (f32x4){0.f, 0.f, 0.f, 0.f};
#pragma unroll
    for (int kk = 0; kk < 2; ++kk) {
        int k0 = wave * 64 + kk * 32;
        bf16x8 af[2], bfr[4];
#pragma unroll
        for (int mi = 0; mi < 2; ++mi) {
            int row = mi * 16 + (lane & 15);
            af[mi] = *(const bf16x8*)(Pl + row * PPITCH + k0 + kslot * 8);
        }
#pragma unroll
        for (int ni = 0; ni < 4; ++ni) {
            int brow = ni * 16 + (lane & 15);
            bfr[ni] = *(const bf16x8*)(wbh + brow * 256 + k0 + kslot * 8);
        }
#pragma unroll
        for (int mi = 0; mi < 2; ++mi)
#pragma unroll
            for (int ni = 0; ni < 4; ++ni)
                acc2[mi][ni] = __builtin_amdgcn_mfma_f32_16x16x32_bf16(
                    af[mi], bfr[ni], acc2[mi][ni], 0, 0, 0);
    }
    __syncthreads();   // all Pl reads complete before red overlays smem

    // ---- phase 2b: deterministic 4-wave f32 reduce (pitch 68, 2-way) ----
    for (int w = 0; w < 4; ++w) {
        if (wave == w) {
#pragma unroll
            for (int mi = 0; mi < 2; ++mi)
#pragma unroll
                for (int ni = 0; ni < 4; ++ni)
#pragma unroll
                    for (int r = 0; r < 4; ++r) {
                        int row = mi * 16 + (lane >> 4) * 4 + r;
                        int col = ni * 16 + (lane & 15);
                        if (w == 0) red[row * RPITCH + col] = acc2[mi][ni][r];
                        else        red[row * RPITCH + col] += acc2[mi][ni][r];
                    }
        }
        __syncthreads();
    }

    // ---- epilogue: + conv (bf16, QKV k-slot), round, vectorized write ----
    {
        const int row = tid >> 3;              // 0..31
        const int col0 = (tid & 7) * 8;        // 0,8,...,56
        const ll nrow = (ll)(q0 + row);
        const bh16* cv = qkv + (ll)b * SMPq + nrow * 1536 + 512 + h * 64 + col0;
        bh16* op = aout + (ll)b * (NVEC * 512) + nrow * 512 + h * 64 + col0;
        bf16x8 c0 = *(const bf16x8*)cv;
        bf16x8 o0;
#pragma unroll
        for (int j = 0; j < 8; ++j)
            o0[j] = (bh16)(red[row * RPITCH + col0 + j] + (float)c0[j]);
        *(bf16x8*)op = o0;
    }
}

// ===========================================================================
// Small kernels
// ===========================================================================
__global__ void embed_k(const float* __restrict__ x, const float* __restrict__ w,
                        const float* __restrict__ b, float* __restrict__ h)
{
    ll idx = (ll)blockIdx.x * 256 + threadIdx.x;
    int d = (int)(idx & 511);
    ll bn = idx >> 9;
    h[idx] = x[bn * 2] * w[d] + x[bn * 2 + 1] * w[512 + d] + b[d];
}

__global__ void __launch_bounds__(256)
ln_k(const float* __restrict__ X, const float* __restrict__ g,
     const float* __restrict__ bta, bh16* __restrict__ Y)
{
    const ll row = blockIdx.x;
    const float* x = X + row * 512;
    bh16* y = Y + row * 512;
    const int tid = threadIdx.x;
    float v0 = x[tid], v1 = x[tid + 256];
    float s = v0 + v1;
    float q = v0 * v0 + v1 * v1;
    __shared__ float sred[8];
    for (int o = 32; o; o >>= 1) { s += __shfl_down(s, o); q += __shfl_down(q, o); }
    const int lane = tid & 63, w = tid >> 6;
    if (lane == 0) { sred[w] = s; sred[4 + w] = q; }
    __syncthreads();
    float ssum = sred[0] + sred[1] + sred[2] + sred[3];
    float qsum = sred[4] + sred[5] + sred[6] + sred[7];
    float mu = ssum * (1.0f / 512.0f);
    float var = qsum * (1.0f / 512.0f) - mu * mu;
    float r = rsqrtf(var + 1e-5f);
    y[tid] = (bh16)((v0 - mu) * r * g[tid] + bta[tid]);
    y[tid + 256] = (bh16)((v1 - mu) * r * g[tid + 256] + bta[tid + 256]);
}

__global__ void __launch_bounds__(256)
cvtT_k(const float* __restrict__ in, bh16* __restrict__ outp, int C, int R)
{
    __shared__ float t[64][65];
    const int nCt = C >> 6;
    const int c0 = (blockIdx.x % nCt) * 64;
    const int r0 = (blockIdx.x / nCt) * 64;
    const int tid = threadIdx.x;
#pragma unroll
    for (int j = 0; j < 16; ++j) {
        int idx = j * 256 + tid;
        int lr = idx >> 6, lc = idx & 63;
        t[lc][lr] = in[(ll)(r0 + lr) * C + c0 + lc];
    }
    __syncthreads();
#pragma unroll
    for (int v = 0; v < 2; ++v) {
        int flat = v * 256 + tid;
        int lc = flat >> 3, r8 = (flat & 7) * 8;
        bf16x8 o;
#pragma unroll
        for (int j = 0; j < 8; ++j) o[j] = (bh16)t[lc][r8 + j];
        *(bf16x8*)(outp + (ll)(c0 + lc) * R + r0 + r8) = o;
    }
}

__global__ void landmarks_k(const bh16* __restrict__ qkv,
                            bh16* __restrict__ qlb, bh16* __restrict__ klb)
{
    int idx = blockIdx.x * 256 + threadIdx.x;
    int d = idx & 63;
    int m = (idx >> 6) & 255;
    int h = (idx >> 14) & 7;
    int b = idx >> 17;
    const bh16* base = qkv + (ll)b * (NVEC * 1536) + (ll)(m * LSEG) * 1536 + h * 64 + d;
    float sq = 0.f, sk = 0.f;
#pragma unroll
    for (int l = 0; l < LSEG; ++l) {
        sq += (float)base[(ll)l * 1536];
        sk += (float)base[(ll)l * 1536 + 512];
    }
    ll o = (ll)(b * 8 + h) * 16384 + m * 64 + d;
    qlb[o] = (bh16)(sq * (0.0625f * 0.125f));
    klb[o] = (bh16)(sk * 0.0625f);
}

__global__ void wbt_k(const bh16* __restrict__ wb, bh16* __restrict__ wbt)
{
    int idx = blockIdx.x * 256 + threadIdx.x;
    int d = idx & 63, kg = (idx >> 6) & 31, bhh = idx >> 11;
    const bh16* p = wb + (ll)bhh * 16384 + kg * 8 * 64 + d;
    bf16x8 o;
#pragma unroll
    for (int j = 0; j < 8; ++j) o[j] = p[j * 64];
    *(bf16x8*)(wbt + (ll)bhh * 16384 + d * 256 + kg * 8) = o;
}

// reduce split-K partials for a 2-sample chunk:
// part [2][8h][8s][256][64] f32 -> A3Vb bf16 at [bh0+smp*8+h][256][64]
__global__ void a3vred_k(const float* __restrict__ part, bh16* __restrict__ outp)
{
    int idx = blockIdx.x * 256 + threadIdx.x;   // 262144
    int smp = idx >> 17;
    int rest = idx & 131071;
    int h = rest >> 14, o = rest & 16383;
    const float* p = part + (ll)smp * 1048576 + (ll)h * 131072 + o;
    float s = 0.f;
#pragma unroll
    for (int j = 0; j < 8; ++j) s += p[j * 16384];
    outp[(ll)(smp * 8 + h) * 16384 + o] = (bh16)s;
}

__global__ void __launch_bounds__(256)
conv_k(bh16* __restrict__ qkv, const float* __restrict__ cw)
{
    int idx = blockIdx.x * 256 + threadIdx.x;
    int c8 = idx & 63;
    int ng = (idx >> 6) & 1023;
    int b  = idx >> 16;
    const int n0 = ng * 4;
    const int h = c8 >> 3;
    const bh16* v = qkv + (ll)b * (NVEC * 1536) + 1024 + c8 * 8;

    float wreg[KER];
#pragma unroll
    for (int k = 0; k < KER; ++k) wreg[k] = cw[h * KER + k];

    float acc[4][8];
#pragma unroll
    for (int t = 0; t < 4; ++t)
#pragma unroll
        for (int e = 0; e < 8; ++e) acc[t][e] = 0.f;

#pragma unroll
    for (int m = 0; m < 36; ++m) {
        int nn = n0 + m - (KER / 2);
        bf16x8 vv = {};
        if ((unsigned)nn < (unsigned)NVEC)
            vv = *(const bf16x8*)(v + (ll)nn * 1536);
#pragma unroll
        for (int t = 0; t < 4; ++t) {
            constexpr int KMAX = KER - 1;
            int k = m - t;
            if (k >= 0 && k <= KMAX) {
                float wk = wreg[k];
#pragma unroll
                for (int e = 0; e < 8; ++e)
                    acc[t][e] = fmaf((float)vv[e], wk, acc[t][e]);
            }
        }
    }

    bh16* o = qkv + (ll)b * (NVEC * 1536) + (ll)n0 * 1536 + 512 + c8 * 8;
#pragma unroll
    for (int t = 0; t < 4; ++t) {
        bf16x8 ov;
#pragma unroll
        for (int e = 0; e < 8; ++e) ov[e] = (bh16)acc[t][e];
        *(bf16x8*)(o + (ll)t * 1536) = ov;
    }
}

__device__ __forceinline__ float blkmax(float m, float* red, int tid)
{
#pragma unroll
    for (int o = 32; o; o >>= 1) m = fmaxf(m, __shfl_down(m, o));
    if ((tid & 63) == 0) red[tid >> 6] = m;
    __syncthreads();
    m = fmaxf(fmaxf(red[0], red[1]), fmaxf(red[2], red[3]));
    __syncthreads();
    return m;
}
__device__ __forceinline__ float blksum(float s, float* red, int tid)
{
#pragma unroll
    for (int o = 32; o; o >>= 1) s += __shfl_down(s, o);
    if ((tid & 63) == 0) red[tid >> 6] = s;
    __syncthreads();
    s = red[0] + red[1] + red[2] + red[3];
    __syncthreads();
    return s;
}

// in-place bf16 row softmax, L == 4096; one block (256 thr) per row
__global__ void __launch_bounds__(256)
softmax_bf_k(bh16* __restrict__ X, int L)
{
    const ll row = blockIdx.x;
    bh16* x = X + row * (ll)L;
    const int tid = threadIdx.x;
    __shared__ float red[4];
    float v[16];
    bf16x8 a = *(const bf16x8*)(x + tid * 8);
    bf16x8 b = *(const bf16x8*)(x + 2048 + tid * 8);
#pragma unroll
    for (int j = 0; j < 8; ++j) { v[j] = (float)a[j]; v[8 + j] = (float)b[j]; }
    float m = -1e30f;
#pragma unroll
    for (int j = 0; j < 16; ++j) m = fmaxf(m, v[j]);
    m = blkmax(m, red, tid);
    float s = 0.f;
#pragma unroll
    for (int j = 0; j < 16; ++j) { v[j] = __expf(v[j] - m); s += v[j]; }
    s = blksum(s, red, tid);
    float inv = 1.0f / s;
    bf16x8 oa, ob;
#pragma unroll
    for (int j = 0; j < 8; ++j) { oa[j] = (bh16)(v[j] * inv); ob[j] = (bh16)(v[8 + j] * inv); }
    *(bf16x8*)(x + tid * 8) = oa;
    *(bf16x8*)(x + 2048 + tid * 8) = ob;
}

__global__ void __launch_bounds__(256)
pinv_init_k(const bh16* __restrict__ X, bh16* __restrict__ Z)
{
    const ll bh = blockIdx.x;
    const bh16* x = X + bh * 65536;
    bh16* z = Z + bh * 65536;
    const int tid = threadIdx.x;
    float rs = 0.f, cs = 0.f;
    for (int j = 0; j < 256; ++j) {
        rs += fabsf((float)x[tid * 256 + j]);
        cs += fabsf((float)x[j * 256 + tid]);
    }
    __shared__ float rbuf[256], cbuf[256];
    rbuf[tid] = rs; cbuf[tid] = cs;
    __syncthreads();
    for (int o = 128; o; o >>= 1) {
        if (tid < o) {
            rbuf[tid] = fmaxf(rbuf[tid], rbuf[tid + o]);
            cbuf[tid] = fmaxf(cbuf[tid], cbuf[tid + o]);
        }
        __syncthreads();
    }
    float inv = 1.0f / (rbuf[0] * cbuf[0]);
    for (int e = tid; e < 65536; e += 256) {
        int i = e >> 8, j = e & 255;
        z[e] = (bh16)((float)x[j * 256 + i] * inv);
    }
}

__global__ void final_init_k(const float* __restrict__ fb, float* __restrict__ out)
{
    int i = threadIdx.x;
    if (i < BB_ * NCLASS) out[i] = fb[i % NCLASS];
}

__global__ void __launch_bounds__(256)
final_gemv_k(const float* __restrict__ hbuf, const float* __restrict__ w,
             float* __restrict__ out)
{
    const int half = blockIdx.y;
    const int chunk = blockIdx.x;
    const int tid = threadIdx.x;
    const int k0 = chunk * 8192;
    float pc[4][NCLASS] = {};
    for (int e = 0; e < 32; ++e) {
        int k = k0 + e * 256 + tid;
        const float* wr = w + (ll)k * NCLASS;
        float wv[NCLASS];
#pragma unroll
        for (int c = 0; c < NCLASS; ++c) wv[c] = wr[c];
#pragma unroll
        for (int b = 0; b < 4; ++b) {
            float hv = hbuf[(ll)(half * 4 + b) * (NVEC * DIM) + k];
#pragma unroll
            for (int c = 0; c < NCLASS; ++c) pc[b][c] = fmaf(hv, wv[c], pc[b][c]);
        }
    }
    __shared__ float red[4][4][NCLASS];
    const int lane = tid & 63, wv_ = tid >> 6;
#pragma unroll
    for (int b = 0; b < 4; ++b)
#pragma unroll
        for (int c = 0; c < NCLASS; ++c) {
            float s = pc[b][c];
#pragma unroll
            for (int o = 32; o; o >>= 1) s += __shfl_down(s, o);
            if (lane == 0) red[wv_][b][c] = s;
        }
    __syncthreads();
    if (tid < 4 * NCLASS) {
        int b = tid / NCLASS, c = tid % NCLASS;
        float s = red[0][b][c] + red[1][b][c] + red[2][b][c] + red[3][b][c];
        atomicAdd(out + (half * 4 + b) * NCLASS + c, s);
    }
}

// ===========================================================================
extern "C" void kernel_launch(void* const* d_in, const int* in_sizes, int n_in,
                              void* d_out, int out_size, void* d_ws, size_t ws_size,
                              hipStream_t stream)
{
    const float* x      = (const float*)d_in[0];
    const float* lin_w  = (const float*)d_in[1];
    const float* lin_b  = (const float*)d_in[2];
    const float* ln1_g  = (const float*)d_in[3];
    const float* ln1_b  = (const float*)d_in[4];
    const float* qkv_w  = (const float*)d_in[5];
    const float* out_w  = (const float*)d_in[6];
    const float* out_b  = (const float*)d_in[7];
    const float* conv_w = (const float*)d_in[8];
    const float* ln2_g  = (const float*)d_in[9];
    const float* ln2_b  = (const float*)d_in[10];
    const float* ff1_w  = (const float*)d_in[11];
    const float* ff1_b  = (const float*)d_in[12];
    const float* ff2_w  = (const float*)d_in[13];
    const float* ff2_b  = (const float*)d_in[14];
    const float* final_w = (const float*)d_in[15];
    const float* final_b = (const float*)d_in[16];
    float* out = (float*)d_out;
    float* ws  = (float*)d_ws;

    // ---- workspace layout (f32 units), total 56,623,104 f32 = 226.5 MB ----
    float* H    = ws;                                  // [8][4096][512] f32
    bh16*  QKV  = (bh16*)(ws + 16777216);              // [8][4096][1536] bf16
    float* P    = ws + 41943040;                       // pool, 10,485,760 f32
    bh16*  qlbf = (bh16*)(ws + 52428800);              // [64bh][256][64] bf16
    bh16*  klbf = (bh16*)(ws + 52953088);
    bh16*  A3Vb = (bh16*)(ws + 53477376);              // [64bh][256][64] bf16
    bh16*  WBb  = (bh16*)(ws + 54001664);
    bh16*  WBT  = (bh16*)(ws + 54525952);              // [64bh][64][256] bf16
    bh16*  WQT  = (bh16*)(ws + 55050240);              // [1536][512] bf16
    bh16*  WOT  = (bh16*)(ws + 55443456);              // [512][512] bf16
    bh16*  F1WT = (bh16*)(ws + 55574528);              // [2048][512] bf16
    bh16*  F2WT = (bh16*)(ws + 56098816);              // [512][2048] bf16
    if (ws_size < 56623104ULL * 4) return;

    // pool aliases (time-sliced)
    bh16*  XLNall = (bh16*)P;                          // [32768][512] bf16
    bh16*  ATT3c  = (bh16*)P;                          // [16bh][256][4096] bf16
    float* A3Vp   = P + 8388608;                       // [2][8h][8s][256][64] f32
    bh16*  Xbf = (bh16*)P;                             // pinv: 5 x [64][256][256] bf16
    bh16*  Z0  = (bh16*)(P + 2097152);
    bh16*  Z1  = (bh16*)(P + 4194304);
    bh16*  T1  = (bh16*)(P + 6291456);
    bh16*  T2  = (bh16*)(P + 8388608);
    bh16*  AOUTa  = (bh16*)P;                          // [8][4096][512] bf16
    bh16*  XLNc   = (bh16*)P;                          // FFN: [8192][512] bf16
    bh16*  HIDc   = (bh16*)(P + 2097152);              // [2][4096][2048] bf16

    const ll SMP = (ll)NVEC * 1536;

    hipLaunchKernelGGL(embed_k, dim3(65536), dim3(256), 0, stream, x, lin_w, lin_b, H);

    for (int i = 0; i < DEPTH; ++i) {
        const float* wq  = qkv_w + (ll)i * 512 * 1536;
        const float* wo  = out_w + (ll)i * 512 * 512;
        const float* bo  = out_b + (ll)i * 512;
        const float* cw  = conv_w + (ll)i * HEADS * KER;
        const float* g1  = ln1_g + (ll)i * 512;
        const float* b1  = ln1_b + (ll)i * 512;
        const float* g2  = ln2_g + (ll)i * 512;
        const float* b2  = ln2_b + (ll)i * 512;
        const float* f1w = ff1_w + (ll)i * 512 * 2048;
        const float* f1b = ff1_b + (ll)i * 2048;
        const float* f2w = ff2_w + (ll)i * 2048 * 512;
        const float* f2b = ff2_b + (ll)i * 512;

        hipLaunchKernelGGL(cvtT_k, dim3(192), dim3(256), 0, stream, wq, WQT, 1536, 512);
        hipLaunchKernelGGL(cvtT_k, dim3(64), dim3(256), 0, stream, wo, WOT, 512, 512);
        hipLaunchKernelGGL(cvtT_k, dim3(256), dim3(256), 0, stream, f1w, F1WT, 2048, 512);
        hipLaunchKernelGGL(cvtT_k, dim3(256), dim3(256), 0, stream, f2w, F2WT, 512, 2048);

        // LN1 + qkv (M=32768), BK=64
        hipLaunchKernelGGL(ln_k, dim3(32768), dim3(256), 0, stream, H, g1, b1, XLNall);
        mg<2,2,2,0,0,0,1,0,0>(stream, 32768, 1536, 512, XLNall, 512, WQT, 512,
            QKV, 1536, nullptr, nullptr, 1, 1, 0,0, 0,0, 0,0, 1.f, 0.f);

        hipLaunchKernelGGL(landmarks_k, dim3(4096), dim3(256), 0, stream, QKV, qlbf, klbf);

        // ---- attn3 / softmax / a3v in 2-sample chunks (bf16 scores) ----
        for (int c = 0; c < 4; ++c) {
            const bh16* qkvc = QKV + (ll)c * 2 * SMP;
            mg<2,2,2,0,0,0,1,0,0>(stream, 256, 4096, 64,
                qlbf + (ll)c * 262144, 64, qkvc + 512, 1536,
                ATT3c, 4096, nullptr, nullptr, 16, 8,
                131072, 16384, SMP, 64, 8388608LL, 1048576, 1.f, 0.f);
            hipLaunchKernelGGL(softmax_bf_k, dim3(4096), dim3(256), 0, stream, ATT3c, 4096);
            for (int s = 0; s < 2; ++s) {
                mg<4,1,1,1,0,0,0,0,0>(stream, 256, 64, 512,
                    ATT3c + (ll)s * 8 * 1048576, 4096, qkvc + (ll)s * SMP + 1024, 1536,
                    A3Vp + (ll)s * 1048576, 64, nullptr, nullptr, 64, 8,
                    1048576, 512, 64, 512LL * 1536, 131072, 16384, 1.f, 0.f);
            }
            hipLaunchKernelGGL(a3vred_k, dim3(1024), dim3(256), 0, stream,
                               A3Vp, A3Vb + (ll)c * 2 * 131072);
        }

        // conv -> QKV k-slot (k fully consumed above)
        hipLaunchKernelGGL(conv_k, dim3(2048), dim3(256), 0, stream, QKV, cw);

        // ---- pinv (bf16 MFMA, batched 64); X via fused-softmax GEMM ----
        mg<1,4,2,0,0,0,1,0,1>(stream, 256, 256, 64, qlbf, 64, klbf, 64,
            Xbf, 256, nullptr, nullptr, 64, 64, 0, 16384, 0, 16384, 0, 65536, 1.f, 0.f);
        hipLaunchKernelGGL(pinv_init_k, dim3(64), dim3(256), 0, stream, Xbf, Z0);
        bh16* zc = Z0; bh16* zn = Z1;
        for (int it = 0; it < ITERS; ++it) {
            mg<2,2,1,1,0,0,1,1,0>(stream, 256, 256, 256, Xbf, 256, zc, 256,
                T1, 256, T2, nullptr, 64, 64, 0, 65536, 0, 65536, 0, 65536, 1.f, 7.f);
            mg<2,2,1,1,0,0,1,0,0>(stream, 256, 256, 256, T1, 256, T2, 256,
                zn, 256, nullptr, nullptr, 64, 64, 0, 65536, 0, 65536, 0, 65536, -1.f, 15.f);
            mg<2,2,1,1,0,0,1,0,0>(stream, 256, 256, 256, T1, 256, zn, 256,
                T2, 256, nullptr, nullptr, 64, 64, 0, 65536, 0, 65536, 0, 65536, -1.f, 13.f);
            mg<2,2,1,1,0,0,1,0,0>(stream, 256, 256, 256, zc, 256, T2, 256,
                zn, 256, nullptr, nullptr, 64, 64, 0, 65536, 0, 65536, 0, 65536, 0.25f, 0.f);
            bh16* t = zc; zc = zn; zn = t;
        }
        mg<4,1,1,1,0,0,1,0,0>(stream, 256, 64, 256, zc, 256, A3Vb, 64,
            WBb, 64, nullptr, nullptr, 64, 64, 0, 65536, 0, 16384, 0, 16384, 1.f, 0.f);
        hipLaunchKernelGGL(wbt_k, dim3(512), dim3(256), 0, stream, WBb, WBT);

        // ---- fused attn1 + P@wb + conv -> AOUTa; then one out-proj (BK=64) ----
        hipLaunchKernelGGL(fattn_k, dim3(128, 64), dim3(256), 0, stream,
                           QKV, klbf, WBT, AOUTa);
        mg<2,2,2,0,0,1,0,0,0>(stream, 32768, 512, 512, AOUTa, 512, WOT, 512,
            H, 512, nullptr, bo, 1, 1, 0,0, 0,0, 0,0, 1.f, 0.f);

        // ---- FFN in 2-sample chunks (BK=64) ----
        for (int c = 0; c < 4; ++c) {
            float* Hc = H + (ll)c * 2 * 2097152;
            hipLaunchKernelGGL(ln_k, dim3(8192), dim3(256), 0, stream, Hc, g2, b2, XLNc);
            mg<2,2,2,0,1,0,1,0,0>(stream, 8192, 2048, 512, XLNc, 512, F1WT, 512,
                HIDc, 2048, nullptr, f1b, 1, 1, 0,0, 0,0, 0,0, 1.f, 0.f);
            mg<2,2,2,0,0,1,0,0,0>(stream, 8192, 512, 2048, HIDc, 2048, F2WT, 2048,
                Hc, 512, nullptr, f2b, 1, 1, 0,0, 0,0, 0,0, 1.f, 0.f);
        }
    }

    hipLaunchKernelGGL(final_init_k, dim3(1), dim3(128), 0, stream, final_b, out);
    hipLaunchKernelGGL(final_gemv_k, dim3(256, 2), dim3(256), 0, stream, H, final_w, out);
}

// Round 22
// 3001.819 us; speedup vs baseline: 1.0775x; 1.0207x over previous
//
#include <hip/hip_runtime.h>
#include <hip/hip_bf16.h>

// Problem constants
#define BB_ 8
#define NVEC 4096
#define DIM 512
#define HEADS 8
#define DH 64
#define MM_ 256
#define ITERS 6
#define DEPTH 2
#define NCLASS 10
#define KER 33
#define INNER 512
#define LSEG 16  // NVEC / MM_

typedef long long ll;
typedef __bf16 bh16;
typedef __attribute__((ext_vector_type(8))) __bf16 bf16x8;
typedef __attribute__((ext_vector_type(4))) float f32x4;

// ===========================================================================
// MFMA bf16 GEMM. TRB=0 (TN): C = A[M,K] @ B_t[N,K]^T. TRB=1 (NN).
// Tile BM=WR*64 x BN=WC*64, 256 threads = 4 waves (WR*WC==4).
// KH = K-halves (32 each) staged per barrier round; KSTEP = KH*32. Each
// half goes to its OWN LDS plane with the proven linear global_load_lds
// pattern; MFMA chain runs plane 0 then plane 1 -> per-accumulator K-order
// unchanged -> BIT-IDENTICAL results; barriers per K-step halve for KH=2.
// (KH=4 avoided: 64KB LDS occupancy cliff, m132.)
// XCD-bijective block swizzle (m204). SMAX: fused row-softmax (WR==1,
// gridDim.x==1). DUAL: C=acc, C2=diagv*I-acc. Batch: z -> bo=z/BI, bi=z%BI.
// ===========================================================================
template<int WR, int WC, int KH, bool TRB, bool GELU_ACT, bool RESID,
         bool BF16OUT, bool DUAL, bool SMAX>
__global__ void __launch_bounds__(256)
mgemm_k(const bh16* __restrict__ A, const bh16* __restrict__ B,
        const float* __restrict__ bias, void* __restrict__ Cv, void* __restrict__ C2v,
        int K, int lda, int ldb, int ldc,
        int BI, ll sAo, ll sAi, ll sBo, ll sBi, ll sCo, ll sCi,
        float alpha, float diagv)
{
    constexpr int BM = WR * 64, BN = WC * 64;
    constexpr int KSTEP = KH * 32;
    const int bz = blockIdx.z;
    const int bo = bz / BI, bi = bz % BI;
    const bh16* Ab = A + bo * sAo + (ll)bi * sAi;
    const bh16* Bb = B + bo * sBo + (ll)bi * sBi;
    const ll coff = bo * sCo + (ll)bi * sCi;

    const int gx = gridDim.x;
    const int nwg = gx * gridDim.y;
    int flat = blockIdx.y * gx + blockIdx.x;
    {
        int xcd = flat & 7, base = flat >> 3;
        int q = nwg >> 3, rr = nwg & 7;
        flat = (xcd < rr ? xcd * (q + 1) : rr * (q + 1) + (xcd - rr) * q) + base;
    }
    const int m0 = (flat / gx) * BM;
    const int n0 = (flat % gx) * BN;

    const int tid = threadIdx.x;
    const int lane = tid & 63;
    const int wave = tid >> 6;
    const int wr = wave / WC, wc = wave % WC;

    __shared__ bh16 Al[KH * BM * 32];
    __shared__ bh16 Bl[KH * BN * 32];
    __shared__ float srow[SMAX ? 4 * 64 : 4];

    f32x4 acc[4][4];
#pragma unroll
    for (int i = 0; i < 4; ++i)
#pragma unroll
        for (int j = 0; j < 4; ++j) acc[i][j] = (f32x4){0.f, 0.f, 0.f, 0.f};

    const int srowi = tid >> 2;  // 0..63
    const int ssl   = tid & 3;   // 16B slot (linear LDS dest)

    const int rsel  = ((lane & 15) >> 1) & 3;
    const int kslot = lane >> 4;

    for (int k0 = 0; k0 < K; k0 += KSTEP) {
        __syncthreads();
#pragma unroll
        for (int hh = 0; hh < KH; ++hh) {
            bh16* Alp = Al + hh * BM * 32;
            bh16* Blp = Bl + hh * BN * 32;
            const int kk0 = k0 + hh * 32;
#pragma unroll
            for (int i = 0; i < BM / 64; ++i) {
                int row = i * 64 + srowi;
                int gsl = ssl ^ ((row >> 1) & 3);
                __builtin_amdgcn_global_load_lds(
                    (const __attribute__((address_space(1))) unsigned int*)
                        (Ab + (ll)(m0 + row) * lda + kk0 + gsl * 8),
                    (__attribute__((address_space(3))) unsigned int*)
                        (Alp + row * 32 + ssl * 8),
                    16, 0, 0);
            }
            if (!TRB) {
#pragma unroll
                for (int i = 0; i < BN / 64; ++i) {
                    int row = i * 64 + srowi;
                    int gsl = ssl ^ ((row >> 1) & 3);
                    __builtin_amdgcn_global_load_lds(
                        (const __attribute__((address_space(1))) unsigned int*)
                            (Bb + (ll)(n0 + row) * ldb + kk0 + gsl * 8),
                        (__attribute__((address_space(3))) unsigned int*)
                            (Blp + row * 32 + ssl * 8),
                        16, 0, 0);
                }
            } else {
                const int bk = tid >> 3;
                const int nb0 = (tid & 7) * (BN / 8);
#pragma unroll
                for (int v8 = 0; v8 < BN / 64; ++v8) {
                    int nb = nb0 + v8 * 8;
                    bf16x8 v = *(const bf16x8*)(Bb + (ll)(kk0 + bk) * ldb + n0 + nb);
#pragma unroll
                    for (int j = 0; j < 8; ++j) {
                        int n = nb + j;
                        int sl = (bk >> 3) ^ ((n >> 1) & 3);
                        Blp[n * 32 + sl * 8 + (bk & 7)] = v[j];
                    }
                }
            }
        }
        __syncthreads();

#pragma unroll
        for (int hh = 0; hh < KH; ++hh) {
            const bh16* Alp = Al + hh * BM * 32;
            const bh16* Blp = Bl + hh * BN * 32;
            bf16x8 af[4], bfr[4];
#pragma unroll
            for (int mi = 0; mi < 4; ++mi) {
                int row = wr * 64 + mi * 16 + (lane & 15);
                af[mi] = *(const bf16x8*)(Alp + row * 32 + (kslot ^ rsel) * 8);
            }
#pragma unroll
            for (int ni = 0; ni < 4; ++ni) {
                int row = wc * 64 + ni * 16 + (lane & 15);
                bfr[ni] = *(const bf16x8*)(Blp + row * 32 + (kslot ^ rsel) * 8);
            }
#pragma unroll
            for (int mi = 0; mi < 4; ++mi)
#pragma unroll
                for (int ni = 0; ni < 4; ++ni)
                    acc[mi][ni] = __builtin_amdgcn_mfma_f32_16x16x32_bf16(
                        af[mi], bfr[ni], acc[mi][ni], 0, 0, 0);
        }
    }

    if (SMAX) {
        bh16* Cb = (bh16*)Cv;
#pragma unroll
        for (int mi = 0; mi < 4; ++mi)
#pragma unroll
            for (int ni = 0; ni < 4; ++ni)
#pragma unroll
                for (int r = 0; r < 4; ++r) acc[mi][ni][r] *= alpha;
        float mx[4][4];
#pragma unroll
        for (int mi = 0; mi < 4; ++mi)
#pragma unroll
            for (int r = 0; r < 4; ++r) {
                float m_ = acc[mi][0][r];
#pragma unroll
                for (int ni = 1; ni < 4; ++ni) m_ = fmaxf(m_, acc[mi][ni][r]);
#pragma unroll
                for (int msk = 1; msk < 16; msk <<= 1)
                    m_ = fmaxf(m_, __shfl_xor(m_, msk));
                mx[mi][r] = m_;
            }
        if ((lane & 15) == 0) {
#pragma unroll
            for (int mi = 0; mi < 4; ++mi)
#pragma unroll
                for (int r = 0; r < 4; ++r)
                    srow[wc * 64 + mi * 16 + (lane >> 4) * 4 + r] = mx[mi][r];
        }
        __syncthreads();
        float M_[4][4];
#pragma unroll
        for (int mi = 0; mi < 4; ++mi)
#pragma unroll
            for (int r = 0; r < 4; ++r) {
                int row = mi * 16 + (lane >> 4) * 4 + r;
                M_[mi][r] = fmaxf(fmaxf(srow[row], srow[64 + row]),
                                  fmaxf(srow[128 + row], srow[192 + row]));
            }
        __syncthreads();
        float sm[4][4];
#pragma unroll
        for (int mi = 0; mi < 4; ++mi)
#pragma unroll
            for (int r = 0; r < 4; ++r) {
                float s_ = 0.f;
#pragma unroll
                for (int ni = 0; ni < 4; ++ni) {
                    float e = __expf(acc[mi][ni][r] - M_[mi][r]);
                    acc[mi][ni][r] = e;
                    s_ += e;
                }
#pragma unroll
                for (int msk = 1; msk < 16; msk <<= 1)
                    s_ += __shfl_xor(s_, msk);
                sm[mi][r] = s_;
            }
        if ((lane & 15) == 0) {
#pragma unroll
            for (int mi = 0; mi < 4; ++mi)
#pragma unroll
                for (int r = 0; r < 4; ++r)
                    srow[wc * 64 + mi * 16 + (lane >> 4) * 4 + r] = sm[mi][r];
        }
        __syncthreads();
#pragma unroll
        for (int mi = 0; mi < 4; ++mi)
#pragma unroll
            for (int r = 0; r < 4; ++r) {
                int row = mi * 16 + (lane >> 4) * 4 + r;
                float inv = 1.0f / (srow[row] + srow[64 + row] +
                                    srow[128 + row] + srow[192 + row]);
                int rowg = m0 + row;
#pragma unroll
                for (int ni = 0; ni < 4; ++ni) {
                    int colg = n0 + wc * 64 + ni * 16 + (lane & 15);
                    Cb[coff + (ll)rowg * ldc + colg] = (bh16)(acc[mi][ni][r] * inv);
                }
            }
        return;
    }

#pragma unroll
    for (int mi = 0; mi < 4; ++mi) {
#pragma unroll
        for (int ni = 0; ni < 4; ++ni) {
            const int colg = n0 + wc * 64 + ni * 16 + (lane & 15);
            const float bia = (!DUAL && bias) ? bias[colg] : 0.f;
#pragma unroll
            for (int r = 0; r < 4; ++r) {
                const int rowg = m0 + wr * 64 + mi * 16 + (lane >> 4) * 4 + r;
                const float a = acc[mi][ni][r];
                const ll off = coff + (ll)rowg * ldc + colg;
                if (DUAL) {
                    ((bh16*)Cv)[off] = (bh16)a;
                    float w = ((rowg == colg) ? diagv : 0.f) - a;
                    ((bh16*)C2v)[off] = (bh16)w;
                } else {
                    float v = alpha * a + bia;
                    if (diagv != 0.f && rowg == colg) v += diagv;
                    if (GELU_ACT) {
                        float t = tanhf(0.7978845608f * (v + 0.044715f * v * v * v));
                        v = 0.5f * v * (1.0f + t);
                    }
                    if (BF16OUT) {
                        ((bh16*)Cv)[off] = (bh16)v;
                    } else {
                        float* p = (float*)Cv + off;
                        float o = v;
                        if (RESID) o += *p;
                        *p = o;
                    }
                }
            }
        }
    }
}

template<int WR, int WC, int KH, bool TRB, bool G, bool R, bool BO, bool D, bool SX>
static inline void mg(hipStream_t s, int M, int N, int K,
                      const bh16* A, int lda, const bh16* B, int ldb,
                      void* C, int ldc, void* C2, const float* bias,
                      int batch, int BI,
                      ll sAo, ll sAi, ll sBo, ll sBi, ll sCo, ll sCi,
                      float alpha, float diagv)
{
    dim3 grid(N / (WC * 64), M / (WR * 64), batch);
    hipLaunchKernelGGL((mgemm_k<WR, WC, KH, TRB, G, R, BO, D, SX>), grid, dim3(256), 0, s,
                       A, B, bias, C, C2, K, lda, ldb, ldc, BI,
                       sAo, sAi, sBo, sBi, sCo, sCi, alpha, diagv);
}

// ===========================================================================
// Fused attn1. Block = (32 q-rows, one (b,h)) -- measured-optimal q-block
// (TLP sweep: QB64=114us, QB32=99us, QB16=146us).
// ===========================================================================
#define QB_ROWS 32
#define PPITCH 264
#define RPITCH 68
__global__ void __launch_bounds__(256)
fattn_k(const bh16* __restrict__ qkv, const bh16* __restrict__ klb,
        const bh16* __restrict__ wbt, bh16* __restrict__ aout)
{
    const int qb = blockIdx.x;          // 0..127
    const int bh = blockIdx.y;          // 0..63
    const int b = bh >> 3, h = bh & 7;
    const int q0 = qb * QB_ROWS;
    const int tid = threadIdx.x, lane = tid & 63, wave = tid >> 6;
    const ll SMPq = (ll)NVEC * 1536;

    __shared__ __align__(16) char smem[QB_ROWS * PPITCH * 2];  // 16,896 B
    bh16*  Pl  = (bh16*)smem;                                  // phase 1-2a
    float* red = (float*)smem;                                 // phase 2b (aliased)
    __shared__ float srow[4 * QB_ROWS];                        // 512 B

    const bh16* qbase = qkv + (ll)b * SMPq + (ll)q0 * 1536 + h * 64;
    const bh16* klbh = klb + (ll)bh * 16384;
    const bh16* wbh  = wbt + (ll)bh * 16384;

    const int kslot = lane >> 4;

    // ---- phase 1: scores (wave covers cols wave*64..wave*64+63) ----
    f32x4 acc[2][4];
#pragma unroll
    for (int i = 0; i < 2; ++i)
#pragma unroll
        for (int j = 0; j < 4; ++j) acc[i][j] = (f32x4){0.f, 0.f, 0.f, 0.f};
#pragma unroll
    for (int ks = 0; ks < 2; ++ks) {
        int k0 = ks * 32;
        bf16x8 af[2], bfr[4];
#pragma unroll
        for (int mi = 0; mi < 2; ++mi) {
            int row = mi * 16 + (lane & 15);
            af[mi] = *(const bf16x8*)(qbase + (ll)row * 1536 + k0 + kslot * 8);
        }
#pragma unroll
        for (int ni = 0; ni < 4; ++ni) {
            int brow = wave * 64 + ni * 16 + (lane & 15);
            bfr[ni] = *(const bf16x8*)(klbh + brow * 64 + k0 + kslot * 8);
        }
#pragma unroll
        for (int mi = 0; mi < 2; ++mi)
#pragma unroll
            for (int ni = 0; ni < 4; ++ni)
                acc[mi][ni] = __builtin_amdgcn_mfma_f32_16x16x32_bf16(
                    af[mi], bfr[ni], acc[mi][ni], 0, 0, 0);
    }

    // ---- softmax over 256 cols (4 wave-quadrants) ----
#pragma unroll
    for (int mi = 0; mi < 2; ++mi)
#pragma unroll
        for (int ni = 0; ni < 4; ++ni)
#pragma unroll
            for (int r = 0; r < 4; ++r) acc[mi][ni][r] *= 0.125f;
    float mx[2][4];
#pragma unroll
    for (int mi = 0; mi < 2; ++mi)
#pragma unroll
        for (int r = 0; r < 4; ++r) {
            float m_ = acc[mi][0][r];
#pragma unroll
            for (int ni = 1; ni < 4; ++ni) m_ = fmaxf(m_, acc[mi][ni][r]);
#pragma unroll
            for (int msk = 1; msk < 16; msk <<= 1)
                m_ = fmaxf(m_, __shfl_xor(m_, msk));
            mx[mi][r] = m_;
        }
    if ((lane & 15) == 0) {
#pragma unroll
        for (int mi = 0; mi < 2; ++mi)
#pragma unroll
            for (int r = 0; r < 4; ++r)
                srow[wave * QB_ROWS + mi * 16 + (lane >> 4) * 4 + r] = mx[mi][r];
    }
    __syncthreads();
    float M_[2][4];
#pragma unroll
    for (int mi = 0; mi < 2; ++mi)
#pragma unroll
        for (int r = 0; r < 4; ++r) {
            int row = mi * 16 + (lane >> 4) * 4 + r;
            M_[mi][r] = fmaxf(fmaxf(srow[row], srow[QB_ROWS + row]),
                              fmaxf(srow[2 * QB_ROWS + row], srow[3 * QB_ROWS + row]));
        }
    __syncthreads();
    float sm[2][4];
#pragma unroll
    for (int mi = 0; mi < 2; ++mi)
#pragma unroll
        for (int r = 0; r < 4; ++r) {
            float s_ = 0.f;
#pragma unroll
            for (int ni = 0; ni < 4; ++ni) {
                float e = __expf(acc[mi][ni][r] - M_[mi][r]);
                acc[mi][ni][r] = e;
                s_ += e;
            }
#pragma unroll
            for (int msk = 1; msk < 16; msk <<= 1)
                s_ += __shfl_xor(s_, msk);
            sm[mi][r] = s_;
        }
    if ((lane & 15) == 0) {
#pragma unroll
        for (int mi = 0; mi < 2; ++mi)
#pragma unroll
            for (int r = 0; r < 4; ++r)
                srow[wave * QB_ROWS + mi * 16 + (lane >> 4) * 4 + r] = sm[mi][r];
    }
    __syncthreads();
    // normalize + write P (row pitch 264, linear)
#pragma unroll
    for (int mi = 0; mi < 2; ++mi)
#pragma unroll
        for (int r = 0; r < 4; ++r) {
            int row = mi * 16 + (lane >> 4) * 4 + r;
            float inv = 1.0f / (srow[row] + srow[QB_ROWS + row] +
                                srow[2 * QB_ROWS + row] + srow[3 * QB_ROWS + row]);
#pragma unroll
            for (int ni = 0; ni < 4; ++ni) {
                int col = wave * 64 + ni * 16 + (lane & 15);
                Pl[row * PPITCH + col] = (bh16)(acc[mi][ni][r] * inv);
            }
        }
    __syncthreads();

    // ---- phase 2a: wave-K-split MFMA (wave w covers k = w*64 .. w*64+63) ----
    f32x4 acc2[2][4];
#pragma unroll
    for (int i = 0; i < 2; ++i)
#pragma unroll
        for (int j = 0; j < 4; ++j) acc2[i][j] = (f32x4){0.f, 0.f, 0.f, 0.f};
#pragma unroll
    for (int kk = 0; kk < 2; ++kk) {
        int k0 = wave * 64 + kk * 32;
        bf16x8 af[2], bfr[4];
#pragma unroll
        for (int mi = 0; mi < 2; ++mi) {
            int row = mi * 16 + (lane & 15);
            af[mi] = *(const bf16x8*)(Pl + row * PPITCH + k0 + kslot * 8);
        }
#pragma unroll
        for (int ni = 0; ni < 4; ++ni) {
            int brow = ni * 16 + (lane & 15);
            bfr[ni] = *(const bf16x8*)(wbh + brow * 256 + k0 + kslot * 8);
        }
#pragma unroll
        for (int mi = 0; mi < 2; ++mi)
#pragma unroll
            for (int ni = 0; ni < 4; ++ni)
                acc2[mi][ni] = __builtin_amdgcn_mfma_f32_16x16x32_bf16(
                    af[mi], bfr[ni], acc2[mi][ni], 0, 0, 0);
    }
    __syncthreads();   // all Pl reads complete before red overlays smem

    // ---- phase 2b: deterministic 4-wave f32 reduce (pitch 68, 2-way) ----
    for (int w = 0; w < 4; ++w) {
        if (wave == w) {
#pragma unroll
            for (int mi = 0; mi < 2; ++mi)
#pragma unroll
                for (int ni = 0; ni < 4; ++ni)
#pragma unroll
                    for (int r = 0; r < 4; ++r) {
                        int row = mi * 16 + (lane >> 4) * 4 + r;
                        int col = ni * 16 + (lane & 15);
                        if (w == 0) red[row * RPITCH + col] = acc2[mi][ni][r];
                        else        red[row * RPITCH + col] += acc2[mi][ni][r];
                    }
        }
        __syncthreads();
    }

    // ---- epilogue: + conv (bf16, QKV k-slot), round, vectorized write ----
    {
        const int row = tid >> 3;              // 0..31
        const int col0 = (tid & 7) * 8;        // 0,8,...,56
        const ll nrow = (ll)(q0 + row);
        const bh16* cv = qkv + (ll)b * SMPq + nrow * 1536 + 512 + h * 64 + col0;
        bh16* op = aout + (ll)b * (NVEC * 512) + nrow * 512 + h * 64 + col0;
        bf16x8 c0 = *(const bf16x8*)cv;
        bf16x8 o0;
#pragma unroll
        for (int j = 0; j < 8; ++j)
            o0[j] = (bh16)(red[row * RPITCH + col0 + j] + (float)c0[j]);
        *(bf16x8*)op = o0;
    }
}

// ===========================================================================
// Small kernels
// ===========================================================================
__global__ void embed_k(const float* __restrict__ x, const float* __restrict__ w,
                        const float* __restrict__ b, float* __restrict__ h)
{
    ll idx = (ll)blockIdx.x * 256 + threadIdx.x;
    int d = (int)(idx & 511);
    ll bn = idx >> 9;
    h[idx] = x[bn * 2] * w[d] + x[bn * 2 + 1] * w[512 + d] + b[d];
}

__global__ void __launch_bounds__(256)
ln_k(const float* __restrict__ X, const float* __restrict__ g,
     const float* __restrict__ bta, bh16* __restrict__ Y)
{
    const ll row = blockIdx.x;
    const float* x = X + row * 512;
    bh16* y = Y + row * 512;
    const int tid = threadIdx.x;
    float v0 = x[tid], v1 = x[tid + 256];
    float s = v0 + v1;
    float q = v0 * v0 + v1 * v1;
    __shared__ float sred[8];
    for (int o = 32; o; o >>= 1) { s += __shfl_down(s, o); q += __shfl_down(q, o); }
    const int lane = tid & 63, w = tid >> 6;
    if (lane == 0) { sred[w] = s; sred[4 + w] = q; }
    __syncthreads();
    float ssum = sred[0] + sred[1] + sred[2] + sred[3];
    float qsum = sred[4] + sred[5] + sred[6] + sred[7];
    float mu = ssum * (1.0f / 512.0f);
    float var = qsum * (1.0f / 512.0f) - mu * mu;
    float r = rsqrtf(var + 1e-5f);
    y[tid] = (bh16)((v0 - mu) * r * g[tid] + bta[tid]);
    y[tid + 256] = (bh16)((v1 - mu) * r * g[tid + 256] + bta[tid + 256]);
}

__global__ void __launch_bounds__(256)
cvtT_k(const float* __restrict__ in, bh16* __restrict__ outp, int C, int R)
{
    __shared__ float t[64][65];
    const int nCt = C >> 6;
    const int c0 = (blockIdx.x % nCt) * 64;
    const int r0 = (blockIdx.x / nCt) * 64;
    const int tid = threadIdx.x;
#pragma unroll
    for (int j = 0; j < 16; ++j) {
        int idx = j * 256 + tid;
        int lr = idx >> 6, lc = idx & 63;
        t[lc][lr] = in[(ll)(r0 + lr) * C + c0 + lc];
    }
    __syncthreads();
#pragma unroll
    for (int v = 0; v < 2; ++v) {
        int flat = v * 256 + tid;
        int lc = flat >> 3, r8 = (flat & 7) * 8;
        bf16x8 o;
#pragma unroll
        for (int j = 0; j < 8; ++j) o[j] = (bh16)t[lc][r8 + j];
        *(bf16x8*)(outp + (ll)(c0 + lc) * R + r0 + r8) = o;
    }
}

__global__ void landmarks_k(const bh16* __restrict__ qkv,
                            bh16* __restrict__ qlb, bh16* __restrict__ klb)
{
    int idx = blockIdx.x * 256 + threadIdx.x;
    int d = idx & 63;
    int m = (idx >> 6) & 255;
    int h = (idx >> 14) & 7;
    int b = idx >> 17;
    const bh16* base = qkv + (ll)b * (NVEC * 1536) + (ll)(m * LSEG) * 1536 + h * 64 + d;
    float sq = 0.f, sk = 0.f;
#pragma unroll
    for (int l = 0; l < LSEG; ++l) {
        sq += (float)base[(ll)l * 1536];
        sk += (float)base[(ll)l * 1536 + 512];
    }
    ll o = (ll)(b * 8 + h) * 16384 + m * 64 + d;
    qlb[o] = (bh16)(sq * (0.0625f * 0.125f));
    klb[o] = (bh16)(sk * 0.0625f);
}

__global__ void wbt_k(const bh16* __restrict__ wb, bh16* __restrict__ wbt)
{
    int idx = blockIdx.x * 256 + threadIdx.x;
    int d = idx & 63, kg = (idx >> 6) & 31, bhh = idx >> 11;
    const bh16* p = wb + (ll)bhh * 16384 + kg * 8 * 64 + d;
    bf16x8 o;
#pragma unroll
    for (int j = 0; j < 8; ++j) o[j] = p[j * 64];
    *(bf16x8*)(wbt + (ll)bhh * 16384 + d * 256 + kg * 8) = o;
}

// reduce split-K partials for a 2-sample chunk:
// part [2][8h][8s][256][64] f32 -> A3Vb bf16 at [bh0+smp*8+h][256][64]
__global__ void a3vred_k(const float* __restrict__ part, bh16* __restrict__ outp)
{
    int idx = blockIdx.x * 256 + threadIdx.x;   // 262144
    int smp = idx >> 17;
    int rest = idx & 131071;
    int h = rest >> 14, o = rest & 16383;
    const float* p = part + (ll)smp * 1048576 + (ll)h * 131072 + o;
    float s = 0.f;
#pragma unroll
    for (int j = 0; j < 8; ++j) s += p[j * 16384];
    outp[(ll)(smp * 8 + h) * 16384 + o] = (bh16)s;
}

__global__ void __launch_bounds__(256)
conv_k(bh16* __restrict__ qkv, const float* __restrict__ cw)
{
    int idx = blockIdx.x * 256 + threadIdx.x;
    int c8 = idx & 63;
    int ng = (idx >> 6) & 1023;
    int b  = idx >> 16;
    const int n0 = ng * 4;
    const int h = c8 >> 3;
    const bh16* v = qkv + (ll)b * (NVEC * 1536) + 1024 + c8 * 8;

    float wreg[KER];
#pragma unroll
    for (int k = 0; k < KER; ++k) wreg[k] = cw[h * KER + k];

    float acc[4][8];
#pragma unroll
    for (int t = 0; t < 4; ++t)
#pragma unroll
        for (int e = 0; e < 8; ++e) acc[t][e] = 0.f;

#pragma unroll
    for (int m = 0; m < 36; ++m) {
        int nn = n0 + m - (KER / 2);
        bf16x8 vv = {};
        if ((unsigned)nn < (unsigned)NVEC)
            vv = *(const bf16x8*)(v + (ll)nn * 1536);
#pragma unroll
        for (int t = 0; t < 4; ++t) {
            constexpr int KMAX = KER - 1;
            int k = m - t;
            if (k >= 0 && k <= KMAX) {
                float wk = wreg[k];
#pragma unroll
                for (int e = 0; e < 8; ++e)
                    acc[t][e] = fmaf((float)vv[e], wk, acc[t][e]);
            }
        }
    }

    bh16* o = qkv + (ll)b * (NVEC * 1536) + (ll)n0 * 1536 + 512 + c8 * 8;
#pragma unroll
    for (int t = 0; t < 4; ++t) {
        bf16x8 ov;
#pragma unroll
        for (int e = 0; e < 8; ++e) ov[e] = (bh16)acc[t][e];
        *(bf16x8*)(o + (ll)t * 1536) = ov;
    }
}

__device__ __forceinline__ float blkmax(float m, float* red, int tid)
{
#pragma unroll
    for (int o = 32; o; o >>= 1) m = fmaxf(m, __shfl_down(m, o));
    if ((tid & 63) == 0) red[tid >> 6] = m;
    __syncthreads();
    m = fmaxf(fmaxf(red[0], red[1]), fmaxf(red[2], red[3]));
    __syncthreads();
    return m;
}
__device__ __forceinline__ float blksum(float s, float* red, int tid)
{
#pragma unroll
    for (int o = 32; o; o >>= 1) s += __shfl_down(s, o);
    if ((tid & 63) == 0) red[tid >> 6] = s;
    __syncthreads();
    s = red[0] + red[1] + red[2] + red[3];
    __syncthreads();
    return s;
}

// in-place bf16 row softmax, L == 4096; one block (256 thr) per row
__global__ void __launch_bounds__(256)
softmax_bf_k(bh16* __restrict__ X, int L)
{
    const ll row = blockIdx.x;
    bh16* x = X + row * (ll)L;
    const int tid = threadIdx.x;
    __shared__ float red[4];
    float v[16];
    bf16x8 a = *(const bf16x8*)(x + tid * 8);
    bf16x8 b = *(const bf16x8*)(x + 2048 + tid * 8);
#pragma unroll
    for (int j = 0; j < 8; ++j) { v[j] = (float)a[j]; v[8 + j] = (float)b[j]; }
    float m = -1e30f;
#pragma unroll
    for (int j = 0; j < 16; ++j) m = fmaxf(m, v[j]);
    m = blkmax(m, red, tid);
    float s = 0.f;
#pragma unroll
    for (int j = 0; j < 16; ++j) { v[j] = __expf(v[j] - m); s += v[j]; }
    s = blksum(s, red, tid);
    float inv = 1.0f / s;
    bf16x8 oa, ob;
#pragma unroll
    for (int j = 0; j < 8; ++j) { oa[j] = (bh16)(v[j] * inv); ob[j] = (bh16)(v[8 + j] * inv); }
    *(bf16x8*)(x + tid * 8) = oa;
    *(bf16x8*)(x + 2048 + tid * 8) = ob;
}

__global__ void __launch_bounds__(256)
pinv_init_k(const bh16* __restrict__ X, bh16* __restrict__ Z)
{
    const ll bh = blockIdx.x;
    const bh16* x = X + bh * 65536;
    bh16* z = Z + bh * 65536;
    const int tid = threadIdx.x;
    float rs = 0.f, cs = 0.f;
    for (int j = 0; j < 256; ++j) {
        rs += fabsf((float)x[tid * 256 + j]);
        cs += fabsf((float)x[j * 256 + tid]);
    }
    __shared__ float rbuf[256], cbuf[256];
    rbuf[tid] = rs; cbuf[tid] = cs;
    __syncthreads();
    for (int o = 128; o; o >>= 1) {
        if (tid < o) {
            rbuf[tid] = fmaxf(rbuf[tid], rbuf[tid + o]);
            cbuf[tid] = fmaxf(cbuf[tid], cbuf[tid + o]);
        }
        __syncthreads();
    }
    float inv = 1.0f / (rbuf[0] * cbuf[0]);
    for (int e = tid; e < 65536; e += 256) {
        int i = e >> 8, j = e & 255;
        z[e] = (bh16)((float)x[j * 256 + i] * inv);
    }
}

__global__ void final_init_k(const float* __restrict__ fb, float* __restrict__ out)
{
    int i = threadIdx.x;
    if (i < BB_ * NCLASS) out[i] = fb[i % NCLASS];
}

__global__ void __launch_bounds__(256)
final_gemv_k(const float* __restrict__ hbuf, const float* __restrict__ w,
             float* __restrict__ out)
{
    const int half = blockIdx.y;
    const int chunk = blockIdx.x;
    const int tid = threadIdx.x;
    const int k0 = chunk * 8192;
    float pc[4][NCLASS] = {};
    for (int e = 0; e < 32; ++e) {
        int k = k0 + e * 256 + tid;
        const float* wr = w + (ll)k * NCLASS;
        float wv[NCLASS];
#pragma unroll
        for (int c = 0; c < NCLASS; ++c) wv[c] = wr[c];
#pragma unroll
        for (int b = 0; b < 4; ++b) {
            float hv = hbuf[(ll)(half * 4 + b) * (NVEC * DIM) + k];
#pragma unroll
            for (int c = 0; c < NCLASS; ++c) pc[b][c] = fmaf(hv, wv[c], pc[b][c]);
        }
    }
    __shared__ float red[4][4][NCLASS];
    const int lane = tid & 63, wv_ = tid >> 6;
#pragma unroll
    for (int b = 0; b < 4; ++b)
#pragma unroll
        for (int c = 0; c < NCLASS; ++c) {
            float s = pc[b][c];
#pragma unroll
            for (int o = 32; o; o >>= 1) s += __shfl_down(s, o);
            if (lane == 0) red[wv_][b][c] = s;
        }
    __syncthreads();
    if (tid < 4 * NCLASS) {
        int b = tid / NCLASS, c = tid % NCLASS;
        float s = red[0][b][c] + red[1][b][c] + red[2][b][c] + red[3][b][c];
        atomicAdd(out + (half * 4 + b) * NCLASS + c, s);
    }
}

// ===========================================================================
extern "C" void kernel_launch(void* const* d_in, const int* in_sizes, int n_in,
                              void* d_out, int out_size, void* d_ws, size_t ws_size,
                              hipStream_t stream)
{
    const float* x      = (const float*)d_in[0];
    const float* lin_w  = (const float*)d_in[1];
    const float* lin_b  = (const float*)d_in[2];
    const float* ln1_g  = (const float*)d_in[3];
    const float* ln1_b  = (const float*)d_in[4];
    const float* qkv_w  = (const float*)d_in[5];
    const float* out_w  = (const float*)d_in[6];
    const float* out_b  = (const float*)d_in[7];
    const float* conv_w = (const float*)d_in[8];
    const float* ln2_g  = (const float*)d_in[9];
    const float* ln2_b  = (const float*)d_in[10];
    const float* ff1_w  = (const float*)d_in[11];
    const float* ff1_b  = (const float*)d_in[12];
    const float* ff2_w  = (const float*)d_in[13];
    const float* ff2_b  = (const float*)d_in[14];
    const float* final_w = (const float*)d_in[15];
    const float* final_b = (const float*)d_in[16];
    float* out = (float*)d_out;
    float* ws  = (float*)d_ws;

    // ---- workspace layout (f32 units), total 56,623,104 f32 = 226.5 MB ----
    float* H    = ws;                                  // [8][4096][512] f32
    bh16*  QKV  = (bh16*)(ws + 16777216);              // [8][4096][1536] bf16
    float* P    = ws + 41943040;                       // pool, 10,485,760 f32
    bh16*  qlbf = (bh16*)(ws + 52428800);              // [64bh][256][64] bf16
    bh16*  klbf = (bh16*)(ws + 52953088);
    bh16*  A3Vb = (bh16*)(ws + 53477376);              // [64bh][256][64] bf16
    bh16*  WBb  = (bh16*)(ws + 54001664);
    bh16*  WBT  = (bh16*)(ws + 54525952);              // [64bh][64][256] bf16
    bh16*  WQT  = (bh16*)(ws + 55050240);              // [1536][512] bf16
    bh16*  WOT  = (bh16*)(ws + 55443456);              // [512][512] bf16
    bh16*  F1WT = (bh16*)(ws + 55574528);              // [2048][512] bf16
    bh16*  F2WT = (bh16*)(ws + 56098816);              // [512][2048] bf16
    if (ws_size < 56623104ULL * 4) return;

    // pool aliases (time-sliced)
    bh16*  XLNall = (bh16*)P;                          // [32768][512] bf16
    bh16*  ATT3c  = (bh16*)P;                          // [16bh][256][4096] bf16
    float* A3Vp   = P + 8388608;                       // [2][8h][8s][256][64] f32
    bh16*  Xbf = (bh16*)P;                             // pinv: 5 x [64][256][256] bf16
    bh16*  Z0  = (bh16*)(P + 2097152);
    bh16*  Z1  = (bh16*)(P + 4194304);
    bh16*  T1  = (bh16*)(P + 6291456);
    bh16*  T2  = (bh16*)(P + 8388608);
    bh16*  AOUTa  = (bh16*)P;                          // [8][4096][512] bf16
    bh16*  XLNc   = (bh16*)P;                          // FFN: [8192][512] bf16
    bh16*  HIDc   = (bh16*)(P + 2097152);              // [2][4096][2048] bf16

    const ll SMP = (ll)NVEC * 1536;

    hipLaunchKernelGGL(embed_k, dim3(65536), dim3(256), 0, stream, x, lin_w, lin_b, H);

    for (int i = 0; i < DEPTH; ++i) {
        const float* wq  = qkv_w + (ll)i * 512 * 1536;
        const float* wo  = out_w + (ll)i * 512 * 512;
        const float* bo  = out_b + (ll)i * 512;
        const float* cw  = conv_w + (ll)i * HEADS * KER;
        const float* g1  = ln1_g + (ll)i * 512;
        const float* b1  = ln1_b + (ll)i * 512;
        const float* g2  = ln2_g + (ll)i * 512;
        const float* b2  = ln2_b + (ll)i * 512;
        const float* f1w = ff1_w + (ll)i * 512 * 2048;
        const float* f1b = ff1_b + (ll)i * 2048;
        const float* f2w = ff2_w + (ll)i * 2048 * 512;
        const float* f2b = ff2_b + (ll)i * 512;

        hipLaunchKernelGGL(cvtT_k, dim3(192), dim3(256), 0, stream, wq, WQT, 1536, 512);
        hipLaunchKernelGGL(cvtT_k, dim3(64), dim3(256), 0, stream, wo, WOT, 512, 512);
        hipLaunchKernelGGL(cvtT_k, dim3(256), dim3(256), 0, stream, f1w, F1WT, 2048, 512);
        hipLaunchKernelGGL(cvtT_k, dim3(256), dim3(256), 0, stream, f2w, F2WT, 512, 2048);

        // LN1 + qkv (M=32768), BK=64
        hipLaunchKernelGGL(ln_k, dim3(32768), dim3(256), 0, stream, H, g1, b1, XLNall);
        mg<2,2,2,0,0,0,1,0,0>(stream, 32768, 1536, 512, XLNall, 512, WQT, 512,
            QKV, 1536, nullptr, nullptr, 1, 1, 0,0, 0,0, 0,0, 1.f, 0.f);

        hipLaunchKernelGGL(landmarks_k, dim3(4096), dim3(256), 0, stream, QKV, qlbf, klbf);

        // ---- attn3 / softmax / a3v in 2-sample chunks (bf16 scores) ----
        for (int c = 0; c < 4; ++c) {
            const bh16* qkvc = QKV + (ll)c * 2 * SMP;
            mg<2,2,2,0,0,0,1,0,0>(stream, 256, 4096, 64,
                qlbf + (ll)c * 262144, 64, qkvc + 512, 1536,
                ATT3c, 4096, nullptr, nullptr, 16, 8,
                131072, 16384, SMP, 64, 8388608LL, 1048576, 1.f, 0.f);
            hipLaunchKernelGGL(softmax_bf_k, dim3(4096), dim3(256), 0, stream, ATT3c, 4096);
            for (int s = 0; s < 2; ++s) {
                mg<4,1,2,1,0,0,0,0,0>(stream, 256, 64, 512,
                    ATT3c + (ll)s * 8 * 1048576, 4096, qkvc + (ll)s * SMP + 1024, 1536,
                    A3Vp + (ll)s * 1048576, 64, nullptr, nullptr, 64, 8,
                    1048576, 512, 64, 512LL * 1536, 131072, 16384, 1.f, 0.f);
            }
            hipLaunchKernelGGL(a3vred_k, dim3(1024), dim3(256), 0, stream,
                               A3Vp, A3Vb + (ll)c * 2 * 131072);
        }

        // conv -> QKV k-slot (k fully consumed above)
        hipLaunchKernelGGL(conv_k, dim3(2048), dim3(256), 0, stream, QKV, cw);

        // ---- pinv (bf16 MFMA, batched 64); X via fused-softmax GEMM ----
        mg<1,4,2,0,0,0,1,0,1>(stream, 256, 256, 64, qlbf, 64, klbf, 64,
            Xbf, 256, nullptr, nullptr, 64, 64, 0, 16384, 0, 16384, 0, 65536, 1.f, 0.f);
        hipLaunchKernelGGL(pinv_init_k, dim3(64), dim3(256), 0, stream, Xbf, Z0);
        bh16* zc = Z0; bh16* zn = Z1;
        for (int it = 0; it < ITERS; ++it) {
            mg<2,2,2,1,0,0,1,1,0>(stream, 256, 256, 256, Xbf, 256, zc, 256,
                T1, 256, T2, nullptr, 64, 64, 0, 65536, 0, 65536, 0, 65536, 1.f, 7.f);
            mg<2,2,2,1,0,0,1,0,0>(stream, 256, 256, 256, T1, 256, T2, 256,
                zn, 256, nullptr, nullptr, 64, 64, 0, 65536, 0, 65536, 0, 65536, -1.f, 15.f);
            mg<2,2,2,1,0,0,1,0,0>(stream, 256, 256, 256, T1, 256, zn, 256,
                T2, 256, nullptr, nullptr, 64, 64, 0, 65536, 0, 65536, 0, 65536, -1.f, 13.f);
            mg<2,2,2,1,0,0,1,0,0>(stream, 256, 256, 256, zc, 256, T2, 256,
                zn, 256, nullptr, nullptr, 64, 64, 0, 65536, 0, 65536, 0, 65536, 0.25f, 0.f);
            bh16* t = zc; zc = zn; zn = t;
        }
        mg<4,1,2,1,0,0,1,0,0>(stream, 256, 64, 256, zc, 256, A3Vb, 64,
            WBb, 64, nullptr, nullptr, 64, 64, 0, 65536, 0, 16384, 0, 16384, 1.f, 0.f);
        hipLaunchKernelGGL(wbt_k, dim3(512), dim3(256), 0, stream, WBb, WBT);

        // ---- fused attn1 + P@wb + conv -> AOUTa; then one out-proj (BK=64) ----
        hipLaunchKernelGGL(fattn_k, dim3(128, 64), dim3(256), 0, stream,
                           QKV, klbf, WBT, AOUTa);
        mg<2,2,2,0,0,1,0,0,0>(stream, 32768, 512, 512, AOUTa, 512, WOT, 512,
            H, 512, nullptr, bo, 1, 1, 0,0, 0,0, 0,0, 1.f, 0.f);

        // ---- FFN in 2-sample chunks (BK=64) ----
        for (int c = 0; c < 4; ++c) {
            float* Hc = H + (ll)c * 2 * 2097152;
            hipLaunchKernelGGL(ln_k, dim3(8192), dim3(256), 0, stream, Hc, g2, b2, XLNc);
            mg<2,2,2,0,1,0,1,0,0>(stream, 8192, 2048, 512, XLNc, 512, F1WT, 512,
                HIDc, 2048, nullptr, f1b, 1, 1, 0,0, 0,0, 0,0, 1.f, 0.f);
            mg<2,2,2,0,0,1,0,0,0>(stream, 8192, 512, 2048, HIDc, 2048, F2WT, 2048,
                Hc, 512, nullptr, f2b, 1, 1, 0,0, 0,0, 0,0, 1.f, 0.f);
        }
    }

    hipLaunchKernelGGL(final_init_k, dim3(1), dim3(128), 0, stream, final_b, out);
    hipLaunchKernelGGL(final_gemv_k, dim3(256, 2), dim3(256), 0, stream, H, final_w, out);
}